// Round 7
// baseline (962.923 us; speedup 1.0000x reference)
//
#include <hip/hip_runtime.h>
#include <hip/hip_fp16.h>
#include <math.h>

#define NUM_BASIS 8
#define SQRT3 1.7320508075688772f
#define SQRT2 1.4142135623730951f
#define INV_SQRT_DEG 0.17677669529663687f   // 1/sqrt(32)
#define PI_F 3.14159265358979323846f

typedef _Float16 half8 __attribute__((ext_vector_type(8)));
typedef float float4v __attribute__((ext_vector_type(4)));

__device__ __forceinline__ float sigmoidf_(float x) { return 1.0f / (1.0f + __expf(-x)); }
__device__ __forceinline__ float siluf_(float x) { return x * sigmoidf_(x); }

__device__ __forceinline__ void unp2(unsigned u, float& a, float& b) {
    __half2 h = *reinterpret_cast<__half2*>(&u);
    float2 f = __half22float2(h);
    a = f.x; b = f.y;
}
__device__ __forceinline__ unsigned pk2(float a, float b) {
    __half2 h = __floats2half2_rn(a, b);
    return *reinterpret_cast<unsigned*>(&h);
}

// ---------------------------------------------------------------------------
// CSR build: degree count (4 edges/thread) -> scan (fused with weight prep)
// ---------------------------------------------------------------------------
__global__ __launch_bounds__(256) void count_deg(
    const int* __restrict__ dst, int* __restrict__ deg, int E)
{
    int base = (blockIdx.x * blockDim.x + threadIdx.x) * 4;
    if (base + 3 < E) {
        int4 d4 = *(const int4*)(dst + base);
        atomicAdd(&deg[d4.x], 1);
        atomicAdd(&deg[d4.y], 1);
        atomicAdd(&deg[d4.z], 1);
        atomicAdd(&deg[d4.w], 1);
    } else {
        for (int e = base; e < E; e++) atomicAdd(&deg[dst[e]], 1);
    }
}

// scan (block 0) fused with weight prep (blocks >= 1).
// R26 prep: w2f (W2 -> f16 B-frag, 1/sqrt3 & 1/sqrt2 folded), wT (f32
// out-major transposes of Wg/Ws/Wv for the fused GEMV), wl12 = Wl1@Wl2.
__global__ __launch_bounds__(1024) void scan_prep(
    const int* __restrict__ deg, int* __restrict__ cursor, int N,
    const float* __restrict__ W2, _Float16* __restrict__ w2f,
    const float* __restrict__ Wg, const float* __restrict__ Ws,
    const float* __restrict__ Wv, float* __restrict__ wT,
    const float* __restrict__ Wl1, const float* __restrict__ Wl2,
    float* __restrict__ wl12)
{
    if (blockIdx.x != 0) {
        int idx = ((int)blockIdx.x - 1) * 1024 + (int)threadIdx.x;
        if (idx < 64) {
            float a = 0.f;
            #pragma unroll
            for (int j = 0; j < 16; j++) a = fmaf(Wl1[idx*16 + j], Wl2[j], a);
            wl12[idx] = a;
        }
        if (idx < 3 * 20480) {
            int L  = idx / 20480;
            int r  = idx % 20480;
            int cg = r / 5120;
            int r2 = r % 5120;
            int p  = r2 / 1024;
            int r3 = r2 % 1024;
            int kh = r3 / 512;
            int r4 = r3 % 512;
            int lane = r4 / 8;
            int j  = r4 % 8;
            int k = kh*32 + (lane >> 4)*8 + j;
            int n = p*64 + cg*16 + (lane & 15);
            float val = W2[(size_t)L*20480 + k*320 + n];
            if (p == 1)      val *= 0.5773502691896258f;   // 1/sqrt(3)
            else if (p == 4) val *= 0.7071067811865476f;   // 1/sqrt(2)
            w2f[idx] = (_Float16)val;
        } else if (idx < 3*20480 + 3*3*4096) {
            int idx2 = idx - 3*20480;
            int L   = idx2 / 12288;
            int rem = idx2 % 12288;
            int mat = rem / 4096;
            int r2  = rem % 4096;
            int o   = r2 >> 6;       // output channel
            int c   = r2 & 63;       // input channel
            const float* src = (mat == 0) ? Wg : (mat == 1) ? Ws : Wv;
            // wT[L][mat][o][c] = W[c][o]  (out-major for per-lane GEMV rows)
            wT[idx2] = src[(size_t)L*4096 + c*64 + o];
        }
        return;
    }

    __shared__ int wsum[16];
    __shared__ int carry_s, tot_s;
    int tid = threadIdx.x;
    int wid = tid >> 6, lane = tid & 63;
    if (tid == 0) carry_s = 0;
    __syncthreads();
    for (int base = 0; base < N; base += 16384) {
        int i0 = base + tid * 16;
        int v[16];
        int sum = 0;
        #pragma unroll
        for (int k = 0; k < 16; k++) {
            int i = i0 + k;
            v[k] = (i < N) ? deg[i] : 0;
            sum += v[k];
        }
        int incl = sum;
        #pragma unroll
        for (int off = 1; off < 64; off <<= 1) {
            int t = __shfl_up(incl, off);
            if (lane >= off) incl += t;
        }
        if (lane == 63) wsum[wid] = incl;
        __syncthreads();
        if (wid == 0 && lane < 16) {
            int wv = wsum[lane];
            int wincl = wv;
            #pragma unroll
            for (int off = 1; off < 16; off <<= 1) {
                int t = __shfl_up(wincl, off);
                if (lane >= off) wincl += t;
            }
            wsum[lane] = wincl - wv;
            if (lane == 15) tot_s = wincl;
        }
        __syncthreads();
        int carry = carry_s;
        int run = carry + wsum[wid] + incl - sum;   // exclusive prefix at i0
        #pragma unroll
        for (int k = 0; k < 16; k++) {
            int i = i0 + k;
            if (i < N) cursor[i] = run;
            run += v[k];
        }
        __syncthreads();
        if (tid == 0) carry_s = carry + tot_s;
        __syncthreads();
    }
}

// Per-edge geometry + radial embedding, scattered directly into CSR slots.
// emb stored f16x8 (16B), y14 stored f16x4 (8B). R26: src-only metadata
// (dst is implicit: the owning node). After this kernel, cursor[i] = row END.
__global__ __launch_bounds__(256) void edge_pre_scatter(
    const float* __restrict__ pos, const int* __restrict__ src,
    const int* __restrict__ dst, const float* __restrict__ cs,
    const float* __restrict__ cell, const int* __restrict__ img,
    int* __restrict__ cursor, _Float16* __restrict__ emb,
    uint2* __restrict__ y14, int* __restrict__ ssrc, int E)
{
    int e = blockIdx.x * blockDim.x + threadIdx.x;
    if (e >= E) return;
    int si = src[e], di = dst[e];
    int slot = atomicAdd(&cursor[di], 1);
    ssrc[slot] = si;
    float vx = pos[di*3+0] - pos[si*3+0];
    float vy = pos[di*3+1] - pos[si*3+1];
    float vz = pos[di*3+2] - pos[si*3+2];
    float c0 = cs[(size_t)e*3+0], c1 = cs[(size_t)e*3+1], c2 = cs[(size_t)e*3+2];
    const float* M = cell + (size_t)img[si] * 9;
    vx += c0*M[0] + c1*M[3] + c2*M[6];
    vy += c0*M[1] + c1*M[4] + c2*M[7];
    vz += c0*M[2] + c1*M[5] + c2*M[8];
    float r  = sqrtf(vx*vx + vy*vy + vz*vz);
    float rs = fmaxf(r, 1e-9f);
    float inv = 1.0f / rs;
    uint2 yv;
    yv.x = pk2(SQRT3*vx*inv, SQRT3*vy*inv);
    yv.y = pk2(SQRT3*vz*inv, 0.f);
    y14[slot] = yv;
    // polynomial cutoff p=6: 1 - 28 x^6 + 48 x^7 - 21 x^8 (0 for x>=1)
    float x = r * (1.0f / 5.0f);
    float x2 = x*x, x6 = x2*x2*x2;
    float fc = 1.0f - 28.0f*x6 + 48.0f*x6*x - 21.0f*x6*x2;
    if (x >= 1.0f) fc = 0.0f;
    float pre = sqrtf(2.0f / 5.0f) * inv * fc;
    float t = PI_F * rs * (1.0f / 5.0f);
    half8 ev;
    #pragma unroll
    for (int n = 1; n <= NUM_BASIS; n++)
        ev[n-1] = (_Float16)(pre * __sinf((float)n * t));
    *(half8*)(emb + (size_t)slot*NUM_BASIS) = ev;
}

// ---------------------------------------------------------------------------
// MLP1 precompute body (R23 grid-strided, weights in registers). Standalone
// kernel + tail-block fusion into fused_layer (when ws affords 2 hA bufs).
// ---------------------------------------------------------------------------
__device__ __forceinline__ void mlp1_pre_body(
    const _Float16* __restrict__ emb, const float* __restrict__ W1,
    const float* __restrict__ B1, _Float16* __restrict__ hA, int E,
    int g, int nthreads)
{
    int kb   = (g & 7) * 8;
    int es   = g >> 3;
    int estr = nthreads >> 3;
    float wv[8][8];
    #pragma unroll
    for (int jj = 0; jj < 8; jj++) {
        float4 a = *(const float4*)(W1 + jj*64 + kb);
        float4 b = *(const float4*)(W1 + jj*64 + kb + 4);
        wv[jj][0]=a.x; wv[jj][1]=a.y; wv[jj][2]=a.z; wv[jj][3]=a.w;
        wv[jj][4]=b.x; wv[jj][5]=b.y; wv[jj][6]=b.z; wv[jj][7]=b.w;
    }
    float bv[8];
    {
        float4 a = *(const float4*)(B1 + kb);
        float4 b = *(const float4*)(B1 + kb + 4);
        bv[0]=a.x; bv[1]=a.y; bv[2]=a.z; bv[3]=a.w;
        bv[4]=b.x; bv[5]=b.y; bv[6]=b.z; bv[7]=b.w;
    }
    for (int e = es; e < E; e += estr) {
        half8 ev = *(const half8*)(emb + (size_t)e*8);
        float hv[8];
        #pragma unroll
        for (int j = 0; j < 8; j++) hv[j] = bv[j];
        #pragma unroll
        for (int jj = 0; jj < 8; jj++) {
            float em = (float)ev[jj];
            #pragma unroll
            for (int j = 0; j < 8; j++)
                hv[j] = fmaf(em, wv[jj][j], hv[j]);
        }
        half8 out;
        #pragma unroll
        for (int j = 0; j < 8; j++) out[j] = (_Float16)siluf_(hv[j]);
        *(half8*)(hA + (size_t)e*64 + kb) = out;
    }
}

__global__ __launch_bounds__(256) void mlp1_pre(
    const _Float16* __restrict__ emb, const float* __restrict__ W1,
    const float* __restrict__ B1, _Float16* __restrict__ hA, int E)
{
    int g = blockIdx.x * blockDim.x + threadIdx.x;
    mlp1_pre_body(emb, W1, B1, hA, E, g, gridDim.x * blockDim.x);
}

// ---------------------------------------------------------------------------
// R26: node-centric fused layer. One wave per node: loops its CSR edges in
// 16-edge MFMA tiles, accumulates messages in registers (valf-masked), then
// does the node update in-kernel (LDS transpose -> f32 GEMV vs Wg/Ws/Wv ->
// gated residual -> nf write; energy on MODE 2). No atomics, no agg buffer,
// no mid-kernel barriers (full B-frag staged: 40 KB general / 16 KB MODE0).
// nf double-buffered (nf_in -> nf_out) to avoid in-place RAW across waves.
// MODE: 0 = first layer (v==0, s from wlin[type]); 1 = middle; 2 = last.
// Tail blocks (blockIdx >= nb_main) run mlp1_pre for the NEXT layer.
// ---------------------------------------------------------------------------
template<int MODE>
__global__ __launch_bounds__(512) void fused_layer(
    const _Float16* __restrict__ hA, const uint2* __restrict__ y14,
    const int* __restrict__ ssrc, const int* __restrict__ rowend,
    const uint2* __restrict__ nf_in, uint2* __restrict__ nf_out,
    const int* __restrict__ type, const float* __restrict__ wlin,
    const _Float16* __restrict__ w2f_L,
    const float* __restrict__ wgT, const float* __restrict__ wsT,
    const float* __restrict__ wvT,
    const float* __restrict__ wl12, float* __restrict__ out, int N,
    const _Float16* __restrict__ emb, const float* __restrict__ W1n,
    const float* __restrict__ B1n, _Float16* __restrict__ hAn, int E,
    int nb_main)
{
    if ((int)blockIdx.x >= nb_main) {
        int g = ((int)blockIdx.x - nb_main) * 512 + (int)threadIdx.x;
        mlp1_pre_body(emb, W1n, B1n, hAn, E, g,
                      ((int)gridDim.x - nb_main) * 512);
        return;
    }

    constexpr int WSZ = (MODE == 0) ? 8192 : 20480;
    __shared__ _Float16 w2s[WSZ];
    __shared__ float aggl[8][4][64];   // [wave][plane s,x,y,z][channel]
    {
        half8* dstv = (half8*)w2s;
        const half8* srcv = (const half8*)w2f_L;
        if (MODE == 0) {
            // paths {0,2} only: [cg][pp][kh][512]
            #pragma unroll
            for (int k = 0; k < 2; k++) {
                int t  = (int)threadIdx.x + k*512;
                int cg = t >> 8;
                int r  = t & 255;
                int pp = r >> 7;
                int rk = r & 127;
                dstv[t] = srcv[cg*640 + pp*256 + rk];
            }
        } else {
            #pragma unroll
            for (int k = 0; k < 5; k++)
                dstv[threadIdx.x + k*512] = srcv[threadIdx.x + k*512];
        }
    }
    __syncthreads();

    int widx = threadIdx.x >> 6;
    int lane = threadIdx.x & 63;
    int q = lane >> 4, col = lane & 15;
    int n = blockIdx.x * 8 + widx;
    bool nv = n < N;
    int nn = nv ? n : 0;
    int rs = (nn > 0) ? rowend[nn-1] : 0;
    int re = rowend[nn];

    float fss[4] = {0,0,0,0}, fsx[4] = {0,0,0,0};
    float fsy[4] = {0,0,0,0}, fsz[4] = {0,0,0,0};

    for (int tb = rs; tb < re; tb += 16) {
        int eA = tb + col;
        if (eA >= re) eA = re - 1;
        const _Float16* hp = hA + (size_t)eA*64 + q*8;
        half8 af0 = *(const half8*)(hp);
        half8 af1 = *(const half8*)(hp + 32);

        int si4[4], tt4[4];
        float valf[4];
        float y1x[4], y1y[4], y1z[4];
        #pragma unroll
        for (int r = 0; r < 4; r++) {
            int e = tb + q*4 + r;
            bool v = e < re;
            valf[r] = v ? 1.f : 0.f;
            if (!v) e = re - 1;
            si4[r] = ssrc[e];
            uint2 yv = y14[e];
            float du;
            unp2(yv.x, y1x[r], y1y[r]);
            unp2(yv.y, y1z[r], du);
        }
        uint2 pf[4][2];
        if (MODE != 0) {
            #pragma unroll
            for (int r = 0; r < 4; r++) {
                size_t nb = (size_t)si4[r]*64 + col;
                pf[r][0] = nf_in[nb];
                pf[r][1] = nf_in[nb + 16];
            }
        } else {
            #pragma unroll
            for (int r = 0; r < 4; r++) tt4[r] = type[si4[r]];
        }

        #pragma unroll
        for (int cgh = 0; cgh < 2; cgh++) {
            if (MODE != 0 && cgh == 1) {
                #pragma unroll
                for (int r = 0; r < 4; r++) {
                    size_t nb = (size_t)si4[r]*64 + 32 + col;
                    pf[r][0] = nf_in[nb];
                    pf[r][1] = nf_in[nb + 16];
                }
            }
            #pragma unroll
            for (int cgl = 0; cgl < 2; cgl++) {
                int cg = cgh*2 + cgl;
                int c  = cg*16 + col;
                float ms[4], mx[4], my[4], mz[4];
                if (MODE == 0) {
                    float4v a1 = {0,0,0,0}, a3 = {0,0,0,0};
                    const _Float16* wbp = w2s + (size_t)cg*2048 + (size_t)lane*8;
                    half8 b10 = *(const half8*)(wbp + 0*512);
                    half8 b11 = *(const half8*)(wbp + 1*512);
                    half8 b30 = *(const half8*)(wbp + 2*512);
                    half8 b31 = *(const half8*)(wbp + 3*512);
                    a1 = __builtin_amdgcn_mfma_f32_16x16x32_f16(af0, b10, a1, 0, 0, 0);
                    a1 = __builtin_amdgcn_mfma_f32_16x16x32_f16(af1, b11, a1, 0, 0, 0);
                    a3 = __builtin_amdgcn_mfma_f32_16x16x32_f16(af0, b30, a3, 0, 0, 0);
                    a3 = __builtin_amdgcn_mfma_f32_16x16x32_f16(af1, b31, a3, 0, 0, 0);
                    #pragma unroll
                    for (int r = 0; r < 4; r++) {
                        float s = wlin[tt4[r]*64 + c];
                        float w3s = a3[r] * s;
                        ms[r] = a1[r] * s;
                        mx[r] = w3s * y1x[r];
                        my[r] = w3s * y1y[r];
                        mz[r] = w3s * y1z[r];
                    }
                } else {
                    float4v acc[5];
                    #pragma unroll
                    for (int p = 0; p < 5; p++) acc[p] = (float4v){0.f,0.f,0.f,0.f};
                    const _Float16* wbp = w2s + (size_t)cg*5120 + (size_t)lane*8;
                    #pragma unroll
                    for (int p = 0; p < 5; p++) {
                        half8 bf0 = *(const half8*)(wbp + ((size_t)(p*2 + 0))*512);
                        half8 bf1 = *(const half8*)(wbp + ((size_t)(p*2 + 1))*512);
                        acc[p] = __builtin_amdgcn_mfma_f32_16x16x32_f16(af0, bf0, acc[p], 0, 0, 0);
                        acc[p] = __builtin_amdgcn_mfma_f32_16x16x32_f16(af1, bf1, acc[p], 0, 0, 0);
                    }
                    #pragma unroll
                    for (int r = 0; r < 4; r++) {
                        float fsxv, fvx, fvy, fvz;
                        unp2(pf[r][cgl].x, fsxv, fvx);
                        unp2(pf[r][cgl].y, fvy, fvz);
                        float yx = y1x[r], yy = y1y[r], yz = y1z[r];
                        float w1 = acc[0][r], w2 = acc[1][r], w3 = acc[2][r];
                        float w4 = acc[3][r], w5 = acc[4][r];
                        float vdoty = fvx*yx + fvy*yy + fvz*yz;
                        ms[r] = fmaf(w1, fsxv, w2*vdoty);        // w2 pre-scaled 1/sqrt3
                        float w3s = w3*fsxv;
                        float cx = fvy*yz - fvz*yy;
                        float cy = fvz*yx - fvx*yz;
                        float cz = fvx*yy - fvy*yx;
                        mx[r] = fmaf(w3s, yx, fmaf(w4, fvx, w5*cx));  // w5 pre-scaled 1/sqrt2
                        my[r] = fmaf(w3s, yy, fmaf(w4, fvy, w5*cy));
                        mz[r] = fmaf(w3s, yz, fmaf(w4, fvz, w5*cz));
                    }
                }
                #pragma unroll
                for (int r = 0; r < 4; r++) {
                    fss[cg] = fmaf(valf[r], ms[r], fss[cg]);
                    fsx[cg] = fmaf(valf[r], mx[r], fsx[cg]);
                    fsy[cg] = fmaf(valf[r], my[r], fsy[cg]);
                    fsz[cg] = fmaf(valf[r], mz[r], fsz[cg]);
                }
            }
        }
    }

    // q-reduce (all lanes end with full sums), then plane-sliced LDS store
    #pragma unroll
    for (int cg = 0; cg < 4; cg++) {
        fss[cg] += __shfl_xor(fss[cg], 16); fss[cg] += __shfl_xor(fss[cg], 32);
        fsx[cg] += __shfl_xor(fsx[cg], 16); fsx[cg] += __shfl_xor(fsx[cg], 32);
        fsy[cg] += __shfl_xor(fsy[cg], 16); fsy[cg] += __shfl_xor(fsy[cg], 32);
        fsz[cg] += __shfl_xor(fsz[cg], 16); fsz[cg] += __shfl_xor(fsz[cg], 32);
        float pv = (q == 0) ? fss[cg] : (q == 1) ? fsx[cg]
                 : (q == 2) ? fsy[cg] : fsz[cg];
        aggl[widx][q][cg*16 + col] = pv * INV_SQRT_DEG;
    }
    asm volatile("s_waitcnt lgkmcnt(0)" ::: "memory");
    __builtin_amdgcn_sched_barrier(0);

    // per-lane GEMV: lane l computes output channel l for Wg/Ws/Wv
    const float* agS = &aggl[widx][0][0];
    const float* agX = &aggl[widx][1][0];
    const float* agY = &aggl[widx][2][0];
    const float* agZ = &aggl[widx][3][0];
    int l = lane;
    float gv = 0.f, sv = 0.f, ovx = 0.f, ovy = 0.f, ovz = 0.f;
    #pragma unroll
    for (int cc = 0; cc < 64; cc += 4) {
        float4 aS = *(const float4*)(agS + cc);
        float4 aX = *(const float4*)(agX + cc);
        float4 aY = *(const float4*)(agY + cc);
        float4 aZ = *(const float4*)(agZ + cc);
        float4 g4 = *(const float4*)(wgT + (size_t)l*64 + cc);
        float4 s4 = *(const float4*)(wsT + (size_t)l*64 + cc);
        float4 v4 = *(const float4*)(wvT + (size_t)l*64 + cc);
        gv = fmaf(aS.x, g4.x, gv); gv = fmaf(aS.y, g4.y, gv);
        gv = fmaf(aS.z, g4.z, gv); gv = fmaf(aS.w, g4.w, gv);
        sv = fmaf(aS.x, s4.x, sv); sv = fmaf(aS.y, s4.y, sv);
        sv = fmaf(aS.z, s4.z, sv); sv = fmaf(aS.w, s4.w, sv);
        ovx = fmaf(aX.x, v4.x, ovx); ovx = fmaf(aX.y, v4.y, ovx);
        ovx = fmaf(aX.z, v4.z, ovx); ovx = fmaf(aX.w, v4.w, ovx);
        ovy = fmaf(aY.x, v4.x, ovy); ovy = fmaf(aY.y, v4.y, ovy);
        ovy = fmaf(aY.z, v4.z, ovy); ovy = fmaf(aY.w, v4.w, ovy);
        ovz = fmaf(aZ.x, v4.x, ovz); ovz = fmaf(aZ.y, v4.y, ovz);
        ovz = fmaf(aZ.z, v4.z, ovz); ovz = fmaf(aZ.w, v4.w, ovz);
    }

    // gated residual epilogue
    float sxo, vxo, vyo, vzo;
    if (MODE == 0) {
        sxo = wlin[type[nn]*64 + l];
        vxo = 0.f; vyo = 0.f; vzo = 0.f;
    } else {
        uint2 cur = nf_in[(size_t)nn*64 + l];
        unp2(cur.x, sxo, vxo);
        unp2(cur.y, vyo, vzo);
    }
    float gate = sigmoidf_(gv);
    sxo += siluf_(sv);
    vxo = fmaf(ovx, gate, vxo);
    vyo = fmaf(ovy, gate, vyo);
    vzo = fmaf(ovz, gate, vzo);

    if (MODE != 2) {
        if (nv) {
            uint2 nvv;
            nvv.x = pk2(sxo, vxo);
            nvv.y = pk2(vyo, vzo);
            nf_out[(size_t)nn*64 + l] = nvv;
        }
    } else {
        float e = sxo * wl12[l];
        e += __shfl_xor(e, 1);  e += __shfl_xor(e, 2);
        e += __shfl_xor(e, 4);  e += __shfl_xor(e, 8);
        e += __shfl_xor(e, 16); e += __shfl_xor(e, 32);
        if (nv && lane == 0) out[nn] = e;
    }
}

extern "C" void kernel_launch(void* const* d_in, const int* in_sizes, int n_in,
                              void* d_out, int out_size, void* d_ws, size_t ws_size,
                              hipStream_t stream)
{
    const int*   atom_type = (const int*)  d_in[0];
    const float* pos       = (const float*)d_in[1];
    const int*   src       = (const int*)  d_in[2];
    const int*   dst       = (const int*)  d_in[3];
    const float* cs        = (const float*)d_in[4];
    const float* cell      = (const float*)d_in[5];
    const int*   img       = (const int*)  d_in[6];
    const float* wlin_in   = (const float*)d_in[7];
    const float* mw1       = (const float*)d_in[8];
    const float* mb1       = (const float*)d_in[9];
    const float* mw2       = (const float*)d_in[10];
    const float* wss       = (const float*)d_in[11];
    const float* wsv       = (const float*)d_in[12];
    const float* wg        = (const float*)d_in[13];
    const float* wl1       = (const float*)d_in[14];
    const float* wl2       = (const float*)d_in[15];
    int N = in_sizes[0];
    int E = in_sizes[2];

    char* w = (char*)d_ws;
    _Float16* emb = (_Float16*)w; w += (size_t)E * 8 * sizeof(_Float16);  // 8.2 MB
    uint2*  y14  = (uint2*)w;  w += (size_t)E * sizeof(uint2);            // 4.1 MB
    int*    ssrc = (int*)w;    w += (size_t)E * sizeof(int);              // 2.0 MB
    uint2*  nfA  = (uint2*)w;  w += (size_t)N * 64 * sizeof(uint2);       // 8.2 MB
    uint2*  nfB  = (uint2*)w;  w += (size_t)N * 64 * sizeof(uint2);       // 8.2 MB
    _Float16* w2f = (_Float16*)w; w += (size_t)3 * 20480 * sizeof(_Float16);
    float*  wT   = (float*)w;  w += (size_t)3 * 3 * 4096 * sizeof(float); // 147 KB
    float*  wl12 = (float*)w;  w += 64 * sizeof(float);
    int*    deg  = (int*)w;    w += (size_t)N * sizeof(int);
    int*    curs = (int*)w;    w += (size_t)N * sizeof(int);

    size_t used   = (size_t)(w - (char*)d_ws);
    size_t hbytes = (size_t)E * 64 * sizeof(_Float16);     // 65.5 MB
    _Float16* hA0 = (_Float16*)w;
    bool two_h = (ws_size >= used + 2*hbytes);
    _Float16* hA1 = two_h ? (_Float16*)(w + hbytes) : hA0;

    hipMemsetAsync(deg, 0, (size_t)N * sizeof(int), stream);
    count_deg<<<(E/4 + 255) / 256, 256, 0, stream>>>(dst, deg, E);
    int prep_n = 3*20480 + 3*3*4096;
    scan_prep<<<1 + (prep_n + 1023) / 1024, 1024, 0, stream>>>(
        deg, curs, N, mw2, w2f, wg, wss, wsv, wT, wl1, wl2, wl12);
    edge_pre_scatter<<<(E + 255) / 256, 256, 0, stream>>>(
        pos, src, dst, cs, cell, img, curs, emb, y14, ssrc, E);
    // curs is now the row-END array.

    int nbm  = (N + 7) / 8;        // 8 nodes per 512-thread block
    int tail = 1024;               // fused mlp1_pre tail blocks

    const float* wT0 = wT;
    const float* wT1 = wT + 12288;
    const float* wT2 = wT + 24576;

    mlp1_pre<<<2048, 256, 0, stream>>>(emb, mw1, mb1, hA0, E);   // L0 h

    if (two_h) {
        // L0: reads hA0, writes nfA; tail precomputes L1 h -> hA1
        fused_layer<0><<<nbm + tail, 512, 0, stream>>>(
            hA0, y14, ssrc, curs, nfB, nfA, atom_type, wlin_in,
            w2f, wT0, wT0 + 4096, wT0 + 8192, wl12, (float*)d_out, N,
            emb, mw1 + 512, mb1 + 64, hA1, E, nbm);
        // L1: reads hA1 + nfA, writes nfB; tail precomputes L2 h -> hA0
        fused_layer<1><<<nbm + tail, 512, 0, stream>>>(
            hA1, y14, ssrc, curs, nfA, nfB, atom_type, wlin_in,
            w2f + 20480, wT1, wT1 + 4096, wT1 + 8192, wl12, (float*)d_out, N,
            emb, mw1 + 1024, mb1 + 128, hA0, E, nbm);
        // L2: reads hA0 + nfB, writes energy
        fused_layer<2><<<nbm, 512, 0, stream>>>(
            hA0, y14, ssrc, curs, nfB, nfA, atom_type, wlin_in,
            w2f + 40960, wT2, wT2 + 4096, wT2 + 8192, wl12, (float*)d_out, N,
            emb, mw1, mb1, hA0, E, nbm);
    } else {
        fused_layer<0><<<nbm, 512, 0, stream>>>(
            hA0, y14, ssrc, curs, nfB, nfA, atom_type, wlin_in,
            w2f, wT0, wT0 + 4096, wT0 + 8192, wl12, (float*)d_out, N,
            emb, mw1, mb1, hA0, E, nbm);
        mlp1_pre<<<2048, 256, 0, stream>>>(emb, mw1 + 512, mb1 + 64, hA0, E);
        fused_layer<1><<<nbm, 512, 0, stream>>>(
            hA0, y14, ssrc, curs, nfA, nfB, atom_type, wlin_in,
            w2f + 20480, wT1, wT1 + 4096, wT1 + 8192, wl12, (float*)d_out, N,
            emb, mw1, mb1, hA0, E, nbm);
        mlp1_pre<<<2048, 256, 0, stream>>>(emb, mw1 + 1024, mb1 + 128, hA0, E);
        fused_layer<2><<<nbm, 512, 0, stream>>>(
            hA0, y14, ssrc, curs, nfB, nfA, atom_type, wlin_in,
            w2f + 40960, wT2, wT2 + 4096, wT2 + 8192, wl12, (float*)d_out, N,
            emb, mw1, mb1, hA0, E, nbm);
    }
}

// Round 8
// 489.364 us; speedup vs baseline: 1.9677x; 1.9677x over previous
//
#include <hip/hip_runtime.h>
#include <hip/hip_fp16.h>
#include <math.h>

#define NUM_BASIS 8
#define SQRT3 1.7320508075688772f
#define SQRT2 1.4142135623730951f
#define INV_SQRT_DEG 0.17677669529663687f   // 1/sqrt(32)
#define PI_F 3.14159265358979323846f

typedef _Float16 half8 __attribute__((ext_vector_type(8)));
typedef float float4v __attribute__((ext_vector_type(4)));

__device__ __forceinline__ float sigmoidf_(float x) { return 1.0f / (1.0f + __expf(-x)); }
__device__ __forceinline__ float siluf_(float x) { return x * sigmoidf_(x); }

__device__ __forceinline__ void unp2(unsigned u, float& a, float& b) {
    __half2 h = *reinterpret_cast<__half2*>(&u);
    float2 f = __half22float2(h);
    a = f.x; b = f.y;
}
__device__ __forceinline__ unsigned pk2(float a, float b) {
    __half2 h = __floats2half2_rn(a, b);
    return *reinterpret_cast<unsigned*>(&h);
}

// ---------------------------------------------------------------------------
// CSR build: degree count (4 edges/thread) -> scan (fused with weight prep)
// ---------------------------------------------------------------------------
__global__ __launch_bounds__(256) void count_deg(
    const int* __restrict__ dst, int* __restrict__ deg, int E)
{
    int base = (blockIdx.x * blockDim.x + threadIdx.x) * 4;
    if (base + 3 < E) {
        int4 d4 = *(const int4*)(dst + base);
        atomicAdd(&deg[d4.x], 1);
        atomicAdd(&deg[d4.y], 1);
        atomicAdd(&deg[d4.z], 1);
        atomicAdd(&deg[d4.w], 1);
    } else {
        for (int e = base; e < E; e++) atomicAdd(&deg[dst[e]], 1);
    }
}

// R24: scan (block 0) fused with weight prep (blocks >= 1).
__global__ __launch_bounds__(1024) void scan_prep(
    const int* __restrict__ deg, int* __restrict__ cursor, int N,
    const float* __restrict__ W2, _Float16* __restrict__ w2f,
    const float* __restrict__ Wg, const float* __restrict__ Ws,
    const float* __restrict__ Wv, _Float16* __restrict__ wgtf,
    const float* __restrict__ Wl1, const float* __restrict__ Wl2,
    float* __restrict__ wl12)
{
    if (blockIdx.x != 0) {
        int idx = ((int)blockIdx.x - 1) * 1024 + (int)threadIdx.x;
        if (idx < 64) {
            float a = 0.f;
            #pragma unroll
            for (int j = 0; j < 16; j++) a = fmaf(Wl1[idx*16 + j], Wl2[j], a);
            wl12[idx] = a;
        }
        if (idx < 3 * 20480) {
            int L  = idx / 20480;
            int r  = idx % 20480;
            int cg = r / 5120;
            int r2 = r % 5120;
            int p  = r2 / 1024;
            int r3 = r2 % 1024;
            int kh = r3 / 512;
            int r4 = r3 % 512;
            int lane = r4 / 8;
            int j  = r4 % 8;
            int k = kh*32 + (lane >> 4)*8 + j;
            int n = p*64 + cg*16 + (lane & 15);
            float val = W2[(size_t)L*20480 + k*320 + n];
            if (p == 1)      val *= 0.5773502691896258f;   // 1/sqrt(3)
            else if (p == 4) val *= 0.7071067811865476f;   // 1/sqrt(2)
            w2f[idx] = (_Float16)val;
        } else if (idx < 3*20480 + 3*3*4096) {
            int idx2 = idx - 3*20480;
            int L   = idx2 / 12288;
            int rem = idx2 % 12288;
            int mat = rem / 4096;
            int r2  = rem % 4096;
            int cg  = r2 / 1024;
            int r3  = r2 % 1024;
            int kh  = r3 / 512;
            int r4  = r3 % 512;
            int lane = r4 / 8;
            int j   = r4 % 8;
            int k = kh*32 + (lane >> 4)*8 + j;
            int n = cg*16 + (lane & 15);
            const float* src = (mat == 0) ? Wg : (mat == 1) ? Ws : Wv;
            wgtf[idx2] = (_Float16)src[(size_t)L*4096 + k*64 + n];
        }
        return;
    }

    __shared__ int wsum[16];
    __shared__ int carry_s, tot_s;
    int tid = threadIdx.x;
    int wid = tid >> 6, lane = tid & 63;
    if (tid == 0) carry_s = 0;
    __syncthreads();
    for (int base = 0; base < N; base += 16384) {
        int i0 = base + tid * 16;
        int v[16];
        int sum = 0;
        #pragma unroll
        for (int k = 0; k < 16; k++) {
            int i = i0 + k;
            v[k] = (i < N) ? deg[i] : 0;
            sum += v[k];
        }
        int incl = sum;
        #pragma unroll
        for (int off = 1; off < 64; off <<= 1) {
            int t = __shfl_up(incl, off);
            if (lane >= off) incl += t;
        }
        if (lane == 63) wsum[wid] = incl;
        __syncthreads();
        if (wid == 0 && lane < 16) {
            int wv = wsum[lane];
            int wincl = wv;
            #pragma unroll
            for (int off = 1; off < 16; off <<= 1) {
                int t = __shfl_up(wincl, off);
                if (lane >= off) wincl += t;
            }
            wsum[lane] = wincl - wv;
            if (lane == 15) tot_s = wincl;
        }
        __syncthreads();
        int carry = carry_s;
        int run = carry + wsum[wid] + incl - sum;   // exclusive prefix at i0
        #pragma unroll
        for (int k = 0; k < 16; k++) {
            int i = i0 + k;
            if (i < N) cursor[i] = run;
            run += v[k];
        }
        __syncthreads();
        if (tid == 0) carry_s = carry + tot_s;
        __syncthreads();
    }
}

// Per-edge geometry + radial embedding, scattered directly into CSR slots.
// emb stored f16x8 (16B), y14 stored f16x4 (8B).
__global__ __launch_bounds__(256) void edge_pre_scatter(
    const float* __restrict__ pos, const int* __restrict__ src,
    const int* __restrict__ dst, const float* __restrict__ cs,
    const float* __restrict__ cell, const int* __restrict__ img,
    int* __restrict__ cursor, _Float16* __restrict__ emb,
    uint2* __restrict__ y14, int2* __restrict__ sdp, int E)
{
    int e = blockIdx.x * blockDim.x + threadIdx.x;
    if (e >= E) return;
    int si = src[e], di = dst[e];
    int slot = atomicAdd(&cursor[di], 1);
    sdp[slot] = make_int2(si, di);
    float vx = pos[di*3+0] - pos[si*3+0];
    float vy = pos[di*3+1] - pos[si*3+1];
    float vz = pos[di*3+2] - pos[si*3+2];
    float c0 = cs[(size_t)e*3+0], c1 = cs[(size_t)e*3+1], c2 = cs[(size_t)e*3+2];
    const float* M = cell + (size_t)img[si] * 9;
    vx += c0*M[0] + c1*M[3] + c2*M[6];
    vy += c0*M[1] + c1*M[4] + c2*M[7];
    vz += c0*M[2] + c1*M[5] + c2*M[8];
    float r  = sqrtf(vx*vx + vy*vy + vz*vz);
    float rs = fmaxf(r, 1e-9f);
    float inv = 1.0f / rs;
    uint2 yv;
    yv.x = pk2(SQRT3*vx*inv, SQRT3*vy*inv);
    yv.y = pk2(SQRT3*vz*inv, 0.f);
    y14[slot] = yv;
    // polynomial cutoff p=6: 1 - 28 x^6 + 48 x^7 - 21 x^8 (0 for x>=1)
    float x = r * (1.0f / 5.0f);
    float x2 = x*x, x6 = x2*x2*x2;
    float fc = 1.0f - 28.0f*x6 + 48.0f*x6*x - 21.0f*x6*x2;
    if (x >= 1.0f) fc = 0.0f;
    float pre = sqrtf(2.0f / 5.0f) * inv * fc;
    float t = PI_F * rs * (1.0f / 5.0f);
    half8 ev;
    #pragma unroll
    for (int n = 1; n <= NUM_BASIS; n++)
        ev[n-1] = (_Float16)(pre * __sinf((float)n * t));
    *(half8*)(emb + (size_t)slot*NUM_BASIS) = ev;
}

// ---------------------------------------------------------------------------
// MLP1 precompute body (R23 grid-strided, weights in registers). Standalone
// kernel for L0; the same body runs in tail blocks of node_update (R24).
// ---------------------------------------------------------------------------
__device__ __forceinline__ void mlp1_pre_body(
    const _Float16* __restrict__ emb, const float* __restrict__ W1,
    const float* __restrict__ B1, _Float16* __restrict__ hA, int E,
    int g, int nthreads)
{
    int kb   = (g & 7) * 8;
    int es   = g >> 3;
    int estr = nthreads >> 3;
    float wv[8][8];
    #pragma unroll
    for (int jj = 0; jj < 8; jj++) {
        float4 a = *(const float4*)(W1 + jj*64 + kb);
        float4 b = *(const float4*)(W1 + jj*64 + kb + 4);
        wv[jj][0]=a.x; wv[jj][1]=a.y; wv[jj][2]=a.z; wv[jj][3]=a.w;
        wv[jj][4]=b.x; wv[jj][5]=b.y; wv[jj][6]=b.z; wv[jj][7]=b.w;
    }
    float bv[8];
    {
        float4 a = *(const float4*)(B1 + kb);
        float4 b = *(const float4*)(B1 + kb + 4);
        bv[0]=a.x; bv[1]=a.y; bv[2]=a.z; bv[3]=a.w;
        bv[4]=b.x; bv[5]=b.y; bv[6]=b.z; bv[7]=b.w;
    }
    for (int e = es; e < E; e += estr) {
        half8 ev = *(const half8*)(emb + (size_t)e*8);
        float hv[8];
        #pragma unroll
        for (int j = 0; j < 8; j++) hv[j] = bv[j];
        #pragma unroll
        for (int jj = 0; jj < 8; jj++) {
            float em = (float)ev[jj];
            #pragma unroll
            for (int j = 0; j < 8; j++)
                hv[j] = fmaf(em, wv[jj][j], hv[j]);
        }
        half8 out;
        #pragma unroll
        for (int j = 0; j < 8; j++) out[j] = (_Float16)siluf_(hv[j]);
        *(half8*)(hA + (size_t)e*64 + kb) = out;
    }
}

__global__ __launch_bounds__(256) void mlp1_pre(
    const _Float16* __restrict__ emb, const float* __restrict__ W1,
    const float* __restrict__ B1, _Float16* __restrict__ hA, int E)
{
    int g = blockIdx.x * blockDim.x + threadIdx.x;
    mlp1_pre_body(emb, W1, B1, hA, E, g, gridDim.x * blockDim.x);
}

// ---------------------------------------------------------------------------
// A-frag MLP1 (fallback when workspace can't hold hA)
// ---------------------------------------------------------------------------
__device__ __forceinline__ void mlp1_afrag(
    const _Float16* __restrict__ emb, const float* __restrict__ W1,
    const float* __restrict__ B1, int eA, int q, half8 afrag[2])
{
    half8 ev = *(const half8*)(emb + (size_t)eA*8);
    float em[8];
    #pragma unroll
    for (int j = 0; j < 8; j++) em[j] = (float)ev[j];
    #pragma unroll
    for (int kh = 0; kh < 2; kh++) {
        int kb = kh*32 + q*8;
        float hv[8];
        float4 b0 = *(const float4*)(B1 + kb);
        float4 b1 = *(const float4*)(B1 + kb + 4);
        hv[0]=b0.x; hv[1]=b0.y; hv[2]=b0.z; hv[3]=b0.w;
        hv[4]=b1.x; hv[5]=b1.y; hv[6]=b1.z; hv[7]=b1.w;
        #pragma unroll
        for (int jj = 0; jj < 8; jj++) {
            float4 wa = *(const float4*)(W1 + jj*64 + kb);
            float4 wb = *(const float4*)(W1 + jj*64 + kb + 4);
            hv[0] = fmaf(em[jj], wa.x, hv[0]);
            hv[1] = fmaf(em[jj], wa.y, hv[1]);
            hv[2] = fmaf(em[jj], wa.z, hv[2]);
            hv[3] = fmaf(em[jj], wa.w, hv[3]);
            hv[4] = fmaf(em[jj], wb.x, hv[4]);
            hv[5] = fmaf(em[jj], wb.y, hv[5]);
            hv[6] = fmaf(em[jj], wb.z, hv[6]);
            hv[7] = fmaf(em[jj], wb.w, hv[7]);
        }
        #pragma unroll
        for (int j = 0; j < 8; j++)
            afrag[kh][j] = (_Float16)siluf_(hv[j]);
    }
}

// R27: B-frags read DIRECTLY from global (no LDS staging). w2f is identical
// for every wave -> L1/L2 broadcast; per fragment the wave reads 1 KB
// contiguous (lane*16B). Deletes staging loads, ds_writes, and ALL barriers
// (R21's time-multiplex restage gone); dead waves return early. LDS = 0 ->
// occupancy cap is VGPR-only (8 waves/SIMD at <=64 VGPR).
// R24 uni fast path kept. R26's fused-node structure reverted (spilled).
// ---------------------------------------------------------------------------
// Layer-0 edge kernel: v == 0 exactly -> only w1/w3 paths, 16 MFMA, no nf.
// ---------------------------------------------------------------------------
template<bool PRE>
__global__ __launch_bounds__(256) void edge_msg_mfma_l0(
    const _Float16* __restrict__ emb, const _Float16* __restrict__ hA,
    const uint2* __restrict__ y14, const int2* __restrict__ sdp,
    const int* __restrict__ type, const float* __restrict__ wlin,
    const float* __restrict__ W1, const float* __restrict__ B1,
    const _Float16* __restrict__ w2f,
    float* __restrict__ aggs, float* __restrict__ aggx,
    float* __restrict__ aggy, float* __restrict__ aggz, int E)
{
    int wave  = (blockIdx.x * blockDim.x + threadIdx.x) >> 6;
    int lane  = threadIdx.x & 63;
    int wbase = wave * 16;
    if (wbase >= E) return;
    int q   = lane >> 4;
    int col = lane & 15;

    half8 afrag[2];
    if (PRE) {
        const _Float16* hp = hA + (size_t)(wbase + col)*64 + q*8;
        afrag[0] = *(const half8*)(hp);
        afrag[1] = *(const half8*)(hp + 32);
    }

    int eb = wbase + q*4;
    int d[4], tt[4];
    float y1x[4], y1y[4], y1z[4];
    #pragma unroll
    for (int r = 0; r < 4; r++) {
        int2 sv = sdp[eb + r];
        tt[r] = type[sv.x];
        d[r]  = sv.y;
        uint2 yv = y14[eb + r];
        float dummy;
        unp2(yv.x, y1x[r], y1y[r]);
        unp2(yv.y, y1z[r], dummy);
    }

    if (!PRE) mlp1_afrag(emb, W1, B1, wbase + col, q, afrag);

    int dfirst = __shfl(d[0], 0);
    bool uni = __all(d[3] == dfirst);     // dst-sorted -> all 16 equal

    int dnq = __shfl_down(d[0], 16);      // next quad's first dst
    int nd3 = (q == 3) ? -1 : dnq;        // q3 reg3: forced tail
    int df = d[0], dl = d[3];
    bool U = (df == dl);
    int dlp = __shfl_up(dl, 16);
    bool link = (q > 0) && (dlp == df);

    #pragma unroll
    for (int cg = 0; cg < 4; cg++) {
        float4v a1 = {0,0,0,0}, a3 = {0,0,0,0};
        const _Float16* wbp = w2f + (size_t)cg*5120 + (size_t)lane*8;
        {
            half8 b10 = *(const half8*)(wbp + 0);          // p=0, kh=0
            half8 b11 = *(const half8*)(wbp + 512);        // p=0, kh=1
            half8 b30 = *(const half8*)(wbp + 2048);       // p=2, kh=0
            half8 b31 = *(const half8*)(wbp + 2560);       // p=2, kh=1
            a1 = __builtin_amdgcn_mfma_f32_16x16x32_f16(afrag[0], b10, a1, 0, 0, 0);
            a1 = __builtin_amdgcn_mfma_f32_16x16x32_f16(afrag[1], b11, a1, 0, 0, 0);
            a3 = __builtin_amdgcn_mfma_f32_16x16x32_f16(afrag[0], b30, a3, 0, 0, 0);
            a3 = __builtin_amdgcn_mfma_f32_16x16x32_f16(afrag[1], b31, a3, 0, 0, 0);
        }
        int c = cg*16 + col;

        float ms[4], mx[4], my[4], mz[4];
        #pragma unroll
        for (int r = 0; r < 4; r++) {
            float s = wlin[tt[r]*64 + c];
            float w3s = a3[r] * s;
            ms[r] = a1[r] * s;
            mx[r] = w3s * y1x[r];
            my[r] = w3s * y1y[r];
            mz[r] = w3s * y1z[r];
        }

        if (uni) {
            float fs = (ms[0]+ms[1]) + (ms[2]+ms[3]);
            float fx = (mx[0]+mx[1]) + (mx[2]+mx[3]);
            float fy = (my[0]+my[1]) + (my[2]+my[3]);
            float fz = (mz[0]+mz[1]) + (mz[2]+mz[3]);
            fs += __shfl_xor(fs, 16); fx += __shfl_xor(fx, 16);
            fy += __shfl_xor(fy, 16); fz += __shfl_xor(fz, 16);
            fs += __shfl_xor(fs, 32); fx += __shfl_xor(fx, 32);
            fy += __shfl_xor(fy, 32); fz += __shfl_xor(fz, 32);
            if (q == 0) {
                size_t ai = (size_t)d[0]*64 + c;
                atomicAdd(aggs + ai, fs);
                atomicAdd(aggx + ai, fx);
                atomicAdd(aggy + ai, fy);
                atomicAdd(aggz + ai, fz);
            }
            continue;
        }

        #pragma unroll
        for (int r = 1; r < 4; r++) {
            if (d[r] == d[r-1]) {
                ms[r] += ms[r-1]; mx[r] += mx[r-1];
                my[r] += my[r-1]; mz[r] += mz[r-1];
            }
        }
        // cross-quad carry (chains up to 4 quads -> 3 iterations)
        float Cs = 0.f, Cx = 0.f, Cy = 0.f, Cz = 0.f;
        #pragma unroll
        for (int it = 0; it < 3; it++) {
            float es = ms[3] + (U ? Cs : 0.f);
            float ex = mx[3] + (U ? Cx : 0.f);
            float ey = my[3] + (U ? Cy : 0.f);
            float ez = mz[3] + (U ? Cz : 0.f);
            float ts = __shfl_up(es, 16);
            float tx = __shfl_up(ex, 16);
            float ty = __shfl_up(ey, 16);
            float tz = __shfl_up(ez, 16);
            Cs = link ? ts : 0.f; Cx = link ? tx : 0.f;
            Cy = link ? ty : 0.f; Cz = link ? tz : 0.f;
        }
        bool hr = true;
        #pragma unroll
        for (int r = 0; r < 4; r++) {
            if (r > 0) hr = hr && (d[r] == d[r-1]);
            float fs = ms[r] + (hr ? Cs : 0.f);
            float fx = mx[r] + (hr ? Cx : 0.f);
            float fy = my[r] + (hr ? Cy : 0.f);
            float fz = mz[r] + (hr ? Cz : 0.f);
            int ndx = (r < 3) ? d[r+1] : nd3;
            if (ndx != d[r] && d[r] >= 0) {
                size_t ai = (size_t)d[r]*64 + c;
                atomicAdd(aggs + ai, fs);
                atomicAdd(aggx + ai, fx);
                atomicAdd(aggy + ai, fy);
                atomicAdd(aggz + ai, fz);
            }
        }
    }
}

// ---------------------------------------------------------------------------
// Process two cg's of the general edge kernel; B-frags direct from global.
// w2h points at this half's 2-cg slice of w2f (cgh*10240 elements).
// ---------------------------------------------------------------------------
__device__ __forceinline__ void process_half(
    const _Float16* __restrict__ w2h, const half8 afrag[2],
    const uint2 pf[4][2], const int d[4], int nd3, bool U, bool link,
    bool uni, const float* y1x, const float* y1y, const float* y1z,
    int cgh, int col,
    float* __restrict__ aggs, float* __restrict__ aggx,
    float* __restrict__ aggy, float* __restrict__ aggz)
{
    int lane = threadIdx.x & 63;
    int q = lane >> 4;
    #pragma unroll
    for (int cgl = 0; cgl < 2; cgl++) {
        float4v acc[5];
        #pragma unroll
        for (int p = 0; p < 5; p++) acc[p] = (float4v){0.f, 0.f, 0.f, 0.f};
        const _Float16* wbp = w2h + ((size_t)cgl*5120) + (size_t)lane*8;
        #pragma unroll
        for (int p = 0; p < 5; p++) {
            half8 bf0 = *(const half8*)(wbp + ((size_t)(p*2 + 0))*512);
            half8 bf1 = *(const half8*)(wbp + ((size_t)(p*2 + 1))*512);
            acc[p] = __builtin_amdgcn_mfma_f32_16x16x32_f16(afrag[0], bf0, acc[p], 0, 0, 0);
            acc[p] = __builtin_amdgcn_mfma_f32_16x16x32_f16(afrag[1], bf1, acc[p], 0, 0, 0);
        }
        int c = (cgh*2 + cgl)*16 + col;

        float ms[4], mx[4], my[4], mz[4];
        #pragma unroll
        for (int r = 0; r < 4; r++) {
            float fsx, fvx, fvy, fvz;
            unp2(pf[r][cgl].x, fsx, fvx);
            unp2(pf[r][cgl].y, fvy, fvz);
            float yx = y1x[r], yy = y1y[r], yz = y1z[r];
            float w1 = acc[0][r], w2 = acc[1][r], w3 = acc[2][r];
            float w4 = acc[3][r], w5 = acc[4][r];
            float vdoty = fvx*yx + fvy*yy + fvz*yz;
            ms[r] = fmaf(w1, fsx, w2*vdoty);           // w2 pre-scaled 1/sqrt3
            float w3s = w3*fsx;
            float cx = fvy*yz - fvz*yy;
            float cy = fvz*yx - fvx*yz;
            float cz = fvx*yy - fvy*yx;
            mx[r] = fmaf(w3s, yx, fmaf(w4, fvx, w5*cx));  // w5 pre-scaled 1/sqrt2
            my[r] = fmaf(w3s, yy, fmaf(w4, fvy, w5*cy));
            mz[r] = fmaf(w3s, yz, fmaf(w4, fvz, w5*cz));
        }

        if (uni) {
            float fs = (ms[0]+ms[1]) + (ms[2]+ms[3]);
            float fx = (mx[0]+mx[1]) + (mx[2]+mx[3]);
            float fy = (my[0]+my[1]) + (my[2]+my[3]);
            float fz = (mz[0]+mz[1]) + (mz[2]+mz[3]);
            fs += __shfl_xor(fs, 16); fx += __shfl_xor(fx, 16);
            fy += __shfl_xor(fy, 16); fz += __shfl_xor(fz, 16);
            fs += __shfl_xor(fs, 32); fx += __shfl_xor(fx, 32);
            fy += __shfl_xor(fy, 32); fz += __shfl_xor(fz, 32);
            if (q == 0) {
                size_t ai = (size_t)d[0]*64 + c;
                atomicAdd(aggs + ai, fs);
                atomicAdd(aggx + ai, fx);
                atomicAdd(aggy + ai, fy);
                atomicAdd(aggz + ai, fz);
            }
            continue;
        }

        #pragma unroll
        for (int r = 1; r < 4; r++) {
            if (d[r] == d[r-1]) {
                ms[r] += ms[r-1]; mx[r] += mx[r-1];
                my[r] += my[r-1]; mz[r] += mz[r-1];
            }
        }
        float Cs = 0.f, Cx = 0.f, Cy = 0.f, Cz = 0.f;
        #pragma unroll
        for (int it = 0; it < 3; it++) {
            float es = ms[3] + (U ? Cs : 0.f);
            float ex = mx[3] + (U ? Cx : 0.f);
            float ey = my[3] + (U ? Cy : 0.f);
            float ez = mz[3] + (U ? Cz : 0.f);
            float ts = __shfl_up(es, 16);
            float tx = __shfl_up(ex, 16);
            float ty = __shfl_up(ey, 16);
            float tz = __shfl_up(ez, 16);
            Cs = link ? ts : 0.f; Cx = link ? tx : 0.f;
            Cy = link ? ty : 0.f; Cz = link ? tz : 0.f;
        }
        bool hr = true;
        #pragma unroll
        for (int r = 0; r < 4; r++) {
            if (r > 0) hr = hr && (d[r] == d[r-1]);
            float fs = ms[r] + (hr ? Cs : 0.f);
            float fx = mx[r] + (hr ? Cx : 0.f);
            float fy = my[r] + (hr ? Cy : 0.f);
            float fz = mz[r] + (hr ? Cz : 0.f);
            int ndx = (r < 3) ? d[r+1] : nd3;
            if (ndx != d[r] && d[r] >= 0) {
                size_t ai = (size_t)d[r]*64 + c;
                atomicAdd(aggs + ai, fs);
                atomicAdd(aggx + ai, fx);
                atomicAdd(aggy + ai, fy);
                atomicAdd(aggz + ai, fz);
            }
        }
    }
}

// ---------------------------------------------------------------------------
// General MFMA edge kernel (layers >= 1): one wave per 16 CSR edges, ALL 4
// cg per wave. R27: no LDS, no barriers; B-frags direct from global.
// pf regs reloaded for cols 32-63 between halves (VGPR diet).
// PRE: afrag from hA (2x16B loads issued first). R24 uni fast path.
// ---------------------------------------------------------------------------
template<bool PRE>
__global__ __launch_bounds__(256) void edge_msg_mfma(
    const _Float16* __restrict__ emb, const _Float16* __restrict__ hA,
    const uint2* __restrict__ y14, const int2* __restrict__ sdp,
    const uint2* __restrict__ nf,
    const float* __restrict__ W1, const float* __restrict__ B1,
    const _Float16* __restrict__ w2f,
    float* __restrict__ aggs, float* __restrict__ aggx,
    float* __restrict__ aggy, float* __restrict__ aggz, int E)
{
    int wave  = (blockIdx.x * blockDim.x + threadIdx.x) >> 6;
    int lane  = threadIdx.x & 63;
    int wbase = wave * 16;
    if (wbase >= E) return;
    int q   = lane >> 4;
    int col = lane & 15;

    half8 afrag[2];
    if (PRE) {
        const _Float16* hp = hA + (size_t)(wbase + col)*64 + q*8;
        afrag[0] = *(const half8*)(hp);
        afrag[1] = *(const half8*)(hp + 32);
    }

    int eb = wbase + q*4;
    int d[4], si[4];
    float y1x[4], y1y[4], y1z[4];
    #pragma unroll
    for (int r = 0; r < 4; r++) {
        int2 sv = sdp[eb + r];
        si[r] = sv.x;
        d[r]  = sv.y;
        uint2 yv = y14[eb + r];
        float dummy;
        unp2(yv.x, y1x[r], y1y[r]);
        unp2(yv.y, y1z[r], dummy);
    }

    // nf prefetch for cols 0-31 (R11)
    uint2 pf[4][2];
    #pragma unroll
    for (int r = 0; r < 4; r++) {
        size_t nb = (size_t)si[r] * 64 + col;
        pf[r][0] = nf[nb];
        pf[r][1] = nf[nb + 16];
    }

    if (!PRE) mlp1_afrag(emb, W1, B1, wbase + col, q, afrag);

    int dfirst = __shfl(d[0], 0);
    bool uni = __all(d[3] == dfirst);     // dst-sorted -> all 16 equal

    int dnq = __shfl_down(d[0], 16);
    int nd3 = (q == 3) ? -1 : dnq;
    int df = d[0], dl = d[3];
    bool U = (df == dl);
    int dlp = __shfl_up(dl, 16);
    bool link = (q > 0) && (dlp == df);

    // ---- cg 0,1 ----
    process_half(w2f, afrag, pf, d, nd3, U, link, uni,
                 y1x, y1y, y1z, 0, col, aggs, aggx, aggy, aggz);

    // reload pf with cols 32-63 (latency hides under cg2/3 MFMAs)
    #pragma unroll
    for (int r = 0; r < 4; r++) {
        size_t nb = (size_t)si[r] * 64 + 32 + col;
        pf[r][0] = nf[nb];
        pf[r][1] = nf[nb + 16];
    }

    // ---- cg 2,3 ----
    process_half(w2f + 10240, afrag, pf, d, nd3, U, link, uni,
                 y1x, y1y, y1z, 1, col, aggs, aggx, aggy, aggz);
}

// ---------------------------------------------------------------------------
// MFMA node update: one wave per 16 nodes (R12). wgtf staged in LDS.
// first=1 (L0): residual s from wlin[type], v = 0. Epilogue zeroes agg in
// place; fused energy projection on last layer.
// R24: tail blocks (blockIdx >= nb_node) run mlp1_pre for the NEXT layer.
// ---------------------------------------------------------------------------
__global__ __launch_bounds__(256) void node_update_mfma(
    uint2* __restrict__ nf,
    float* __restrict__ aggs, float* __restrict__ aggx,
    float* __restrict__ aggy, float* __restrict__ aggz,
    const _Float16* __restrict__ wgtf,
    const int* __restrict__ type, const float* __restrict__ wlin,
    const float* __restrict__ wl12,
    float* __restrict__ out, int first, int do_out, int N,
    const _Float16* __restrict__ emb, const float* __restrict__ W1n,
    const float* __restrict__ B1n, _Float16* __restrict__ hA, int E,
    int nb_node)
{
    if ((int)blockIdx.x >= nb_node) {
        int g = ((int)blockIdx.x - nb_node) * 256 + (int)threadIdx.x;
        mlp1_pre_body(emb, W1n, B1n, hA, E, g,
                      ((int)gridDim.x - nb_node) * 256);
        return;
    }

    __shared__ _Float16 wgs[12288];   // 24.6 KB
    {
        half8* dstv = (half8*)wgs;
        const half8* srcv = (const half8*)wgtf;
        #pragma unroll
        for (int k = 0; k < 6; k++)
            dstv[threadIdx.x + k*256] = srcv[threadIdx.x + k*256];
    }

    int wave  = (blockIdx.x * blockDim.x + threadIdx.x) >> 6;
    int lane  = threadIdx.x & 63;
    int wbase = wave * 16;
    bool active = wbase < N;
    int q = lane >> 4, col = lane & 15;

    int nodeA = active ? (wbase + col) : 0;
    if (nodeA >= N) nodeA = N - 1;
    size_t nb = (size_t)nodeA * 64 + q * 8;
    half8 af0[2], af1[2], af2[2], af3[2];
    #pragma unroll
    for (int kh = 0; kh < 2; kh++) {
        const float* p0 = aggs + nb + kh*32;
        const float* p1 = aggx + nb + kh*32;
        const float* p2 = aggy + nb + kh*32;
        const float* p3 = aggz + nb + kh*32;
        float4 a0 = *(const float4*)p0, b0 = *(const float4*)(p0+4);
        float4 a1 = *(const float4*)p1, b1 = *(const float4*)(p1+4);
        float4 a2 = *(const float4*)p2, b2 = *(const float4*)(p2+4);
        float4 a3 = *(const float4*)p3, b3 = *(const float4*)(p3+4);
        af0[kh][0]=(_Float16)(a0.x*INV_SQRT_DEG); af0[kh][1]=(_Float16)(a0.y*INV_SQRT_DEG);
        af0[kh][2]=(_Float16)(a0.z*INV_SQRT_DEG); af0[kh][3]=(_Float16)(a0.w*INV_SQRT_DEG);
        af0[kh][4]=(_Float16)(b0.x*INV_SQRT_DEG); af0[kh][5]=(_Float16)(b0.y*INV_SQRT_DEG);
        af0[kh][6]=(_Float16)(b0.z*INV_SQRT_DEG); af0[kh][7]=(_Float16)(b0.w*INV_SQRT_DEG);
        af1[kh][0]=(_Float16)(a1.x*INV_SQRT_DEG); af1[kh][1]=(_Float16)(a1.y*INV_SQRT_DEG);
        af1[kh][2]=(_Float16)(a1.z*INV_SQRT_DEG); af1[kh][3]=(_Float16)(a1.w*INV_SQRT_DEG);
        af1[kh][4]=(_Float16)(b1.x*INV_SQRT_DEG); af1[kh][5]=(_Float16)(b1.y*INV_SQRT_DEG);
        af1[kh][6]=(_Float16)(b1.z*INV_SQRT_DEG); af1[kh][7]=(_Float16)(b1.w*INV_SQRT_DEG);
        af2[kh][0]=(_Float16)(a2.x*INV_SQRT_DEG); af2[kh][1]=(_Float16)(a2.y*INV_SQRT_DEG);
        af2[kh][2]=(_Float16)(a2.z*INV_SQRT_DEG); af2[kh][3]=(_Float16)(a2.w*INV_SQRT_DEG);
        af2[kh][4]=(_Float16)(b2.x*INV_SQRT_DEG); af2[kh][5]=(_Float16)(b2.y*INV_SQRT_DEG);
        af2[kh][6]=(_Float16)(b2.z*INV_SQRT_DEG); af2[kh][7]=(_Float16)(b2.w*INV_SQRT_DEG);
        af3[kh][0]=(_Float16)(a3.x*INV_SQRT_DEG); af3[kh][1]=(_Float16)(a3.y*INV_SQRT_DEG);
        af3[kh][2]=(_Float16)(a3.z*INV_SQRT_DEG); af3[kh][3]=(_Float16)(a3.w*INV_SQRT_DEG);
        af3[kh][4]=(_Float16)(b3.x*INV_SQRT_DEG); af3[kh][5]=(_Float16)(b3.y*INV_SQRT_DEG);
        af3[kh][6]=(_Float16)(b3.z*INV_SQRT_DEG); af3[kh][7]=(_Float16)(b3.w*INV_SQRT_DEG);
    }

    int tt[4];
    #pragma unroll
    for (int r = 0; r < 4; r++) {
        int nd = wbase + q*4 + r;
        tt[r] = type[(active && nd < N) ? nd : 0];
    }

    __syncthreads();   // wgs staged; all waves arrive

    float epart[4] = {0.f, 0.f, 0.f, 0.f};

    #pragma unroll
    for (int cg = 0; cg < 4; cg++) {
        const _Float16* bp = wgs + (size_t)lane * 8;
        half8 bg0 = *(const half8*)(bp + ((size_t)((0*4 + cg)*2 + 0))*512);
        half8 bg1 = *(const half8*)(bp + ((size_t)((0*4 + cg)*2 + 1))*512);
        half8 bs0 = *(const half8*)(bp + ((size_t)((1*4 + cg)*2 + 0))*512);
        half8 bs1 = *(const half8*)(bp + ((size_t)((1*4 + cg)*2 + 1))*512);
        half8 bv0 = *(const half8*)(bp + ((size_t)((2*4 + cg)*2 + 0))*512);
        half8 bv1 = *(const half8*)(bp + ((size_t)((2*4 + cg)*2 + 1))*512);
        float4v ag = {0,0,0,0}, as = {0,0,0,0};
        float4v ox = {0,0,0,0}, oy = {0,0,0,0}, oz = {0,0,0,0};
        ag = __builtin_amdgcn_mfma_f32_16x16x32_f16(af0[0], bg0, ag, 0, 0, 0);
        ag = __builtin_amdgcn_mfma_f32_16x16x32_f16(af0[1], bg1, ag, 0, 0, 0);
        as = __builtin_amdgcn_mfma_f32_16x16x32_f16(af0[0], bs0, as, 0, 0, 0);
        as = __builtin_amdgcn_mfma_f32_16x16x32_f16(af0[1], bs1, as, 0, 0, 0);
        ox = __builtin_amdgcn_mfma_f32_16x16x32_f16(af1[0], bv0, ox, 0, 0, 0);
        ox = __builtin_amdgcn_mfma_f32_16x16x32_f16(af1[1], bv1, ox, 0, 0, 0);
        oy = __builtin_amdgcn_mfma_f32_16x16x32_f16(af2[0], bv0, oy, 0, 0, 0);
        oy = __builtin_amdgcn_mfma_f32_16x16x32_f16(af2[1], bv1, oy, 0, 0, 0);
        oz = __builtin_amdgcn_mfma_f32_16x16x32_f16(af3[0], bv0, oz, 0, 0, 0);
        oz = __builtin_amdgcn_mfma_f32_16x16x32_f16(af3[1], bv1, oz, 0, 0, 0);

        if (!active) continue;
        int c = cg*16 + col;
        float wlc = wl12[c];
        #pragma unroll
        for (int r = 0; r < 4; r++) {
            int nd = wbase + q*4 + r;
            bool wr = nd < N;
            size_t ni = (size_t)nd*64 + c;
            float sx, vx, vy, vz;
            if (first) {
                sx = wlin[tt[r]*64 + c];
                vx = 0.f; vy = 0.f; vz = 0.f;
            } else {
                uint2 cur = nf[wr ? ni : 0];
                unp2(cur.x, sx, vx);
                unp2(cur.y, vy, vz);
            }
            float gate = sigmoidf_(ag[r]);
            sx += siluf_(as[r]);
            vx += ox[r] * gate;
            vy += oy[r] * gate;
            vz += oz[r] * gate;
            if (wr) {
                uint2 nv;
                nv.x = pk2(sx, vx);
                nv.y = pk2(vy, vz);
                nf[ni] = nv;
                aggs[ni] = 0.f;   // in-place zero replaces per-layer memset
                aggx[ni] = 0.f;
                aggy[ni] = 0.f;
                aggz[ni] = 0.f;
                epart[r] = fmaf(sx, wlc, epart[r]);
            }
        }
    }
    if (do_out && active) {
        #pragma unroll
        for (int r = 0; r < 4; r++) {
            float e = epart[r];
            e += __shfl_xor(e, 1);
            e += __shfl_xor(e, 2);
            e += __shfl_xor(e, 4);
            e += __shfl_xor(e, 8);
            int nd = wbase + q*4 + r;
            if (col == 0 && nd < N) out[nd] = e;
        }
    }
}

extern "C" void kernel_launch(void* const* d_in, const int* in_sizes, int n_in,
                              void* d_out, int out_size, void* d_ws, size_t ws_size,
                              hipStream_t stream)
{
    const int*   atom_type = (const int*)  d_in[0];
    const float* pos       = (const float*)d_in[1];
    const int*   src       = (const int*)  d_in[2];
    const int*   dst       = (const int*)  d_in[3];
    const float* cs        = (const float*)d_in[4];
    const float* cell      = (const float*)d_in[5];
    const int*   img       = (const int*)  d_in[6];
    const float* wlin_in   = (const float*)d_in[7];
    const float* mw1       = (const float*)d_in[8];
    const float* mb1       = (const float*)d_in[9];
    const float* mw2       = (const float*)d_in[10];
    const float* wss       = (const float*)d_in[11];
    const float* wsv       = (const float*)d_in[12];
    const float* wg        = (const float*)d_in[13];
    const float* wl1       = (const float*)d_in[14];
    const float* wl2       = (const float*)d_in[15];
    int N = in_sizes[0];
    int E = in_sizes[2];

    char* w = (char*)d_ws;
    _Float16* emb = (_Float16*)w; w += (size_t)E * 8 * sizeof(_Float16);  // 8.2 MB
    uint2*  y14  = (uint2*)w;  w += (size_t)E * sizeof(uint2);            // 4.1 MB
    int2*   sdp  = (int2*)w;   w += (size_t)E * sizeof(int2);             // 4.1 MB
    uint2*  nf   = (uint2*)w;  w += (size_t)N * 64 * sizeof(uint2);       // 8.2 MB
    float*  agg  = (float*)w;  w += (size_t)N * 64 * 4 * sizeof(float);   // 16.4 MB
    _Float16* w2f  = (_Float16*)w; w += (size_t)3 * 20480 * sizeof(_Float16);
    _Float16* wgtf = (_Float16*)w; w += (size_t)3 * 3 * 4096 * sizeof(_Float16);
    float*  wl12 = (float*)w;  w += 64 * sizeof(float);
    int*    deg  = (int*)w;    w += (size_t)N * sizeof(int);
    int*    curs = (int*)w;    w += (size_t)N * sizeof(int);

    // single hA buffer, written just-in-time before each edge kernel
    // (L3-hot when read). Layers 1/2 write it from node_update's tail
    // blocks; layer 0 uses the standalone pre kernel.
    size_t used   = (size_t)(w - (char*)d_ws);
    size_t hbytes = (size_t)E * 64 * sizeof(_Float16);     // 65.5 MB
    int nh = (ws_size >= used + hbytes) ? 1 : 0;
    _Float16* hbuf = (_Float16*)w;

    size_t NC = (size_t)N * 64;
    float* aggs = agg;
    float* aggx = agg + NC;
    float* aggy = agg + 2*NC;
    float* aggz = agg + 3*NC;

    hipMemsetAsync(deg, 0, (size_t)N * sizeof(int), stream);
    hipMemsetAsync(agg, 0, NC * 4 * sizeof(float), stream);  // L0 only;
                                                             // node_update
                                                             // zeroes in place
    count_deg<<<(E/4 + 255) / 256, 256, 0, stream>>>(dst, deg, E);
    int prep_n = 3*20480 + 3*3*4096;
    scan_prep<<<1 + (prep_n + 1023) / 1024, 1024, 0, stream>>>(
        deg, curs, N, mw2, w2f, wg, wss, wsv, wgtf, wl1, wl2, wl12);
    edge_pre_scatter<<<(E + 255) / 256, 256, 0, stream>>>(
        pos, src, dst, cs, cell, img, curs, emb, y14, sdp, E);

    int eblocks = (E + 63) / 64;   // 4 waves/block, 16 edges/wave
    int nblocks = (N + 63) / 64;   // 4 waves/block, 16 nodes/wave
    int pblocks = 2048;            // grid-strided mlp1_pre (~8 edges/thread)

    // ---- Layer 0: v==0 specialization ----
    if (nh) {
        mlp1_pre<<<pblocks, 256, 0, stream>>>(emb, mw1, mb1, hbuf, E);
        edge_msg_mfma_l0<true><<<eblocks, 256, 0, stream>>>(
            emb, hbuf, y14, sdp, atom_type, wlin_in,
            mw1, mb1, w2f, aggs, aggx, aggy, aggz, E);
    } else {
        edge_msg_mfma_l0<false><<<eblocks, 256, 0, stream>>>(
            emb, nullptr, y14, sdp, atom_type, wlin_in,
            mw1, mb1, w2f, aggs, aggx, aggy, aggz, E);
    }
    // node L0 + (fused) pre for L1
    node_update_mfma<<<nblocks + (nh ? pblocks : 0), 256, 0, stream>>>(
        nf, aggs, aggx, aggy, aggz, wgtf, atom_type, wlin_in, wl12,
        (float*)d_out, 1, 0, N,
        emb, mw1 + 1 * 8 * 64, mb1 + 1 * 64, hbuf, E, nblocks);

    // ---- Layers 1..2 ----
    for (int L = 1; L < 3; L++) {
        if (nh) {
            edge_msg_mfma<true><<<eblocks, 256, 0, stream>>>(
                emb, hbuf, y14, sdp, nf,
                mw1 + L * 8 * 64, mb1 + L * 64, w2f + (size_t)L * 20480,
                aggs, aggx, aggy, aggz, E);
        } else {
            edge_msg_mfma<false><<<eblocks, 256, 0, stream>>>(
                emb, nullptr, y14, sdp, nf,
                mw1 + L * 8 * 64, mb1 + L * 64, w2f + (size_t)L * 20480,
                aggs, aggx, aggy, aggz, E);
        }
        // node L + (fused) pre for L+1 (only when a next layer exists)
        int fuse = (nh && L < 2) ? pblocks : 0;
        node_update_mfma<<<nblocks + fuse, 256, 0, stream>>>(
            nf, aggs, aggx, aggy, aggz,
            wgtf + (size_t)L * 12288, atom_type, wlin_in, wl12,
            (float*)d_out, 0, (L == 2) ? 1 : 0, N,
            emb, mw1 + (L+1 < 3 ? L+1 : 0) * 8 * 64,
            mb1 + (L+1 < 3 ? L+1 : 0) * 64, hbuf, E,
            fuse ? nblocks : (nblocks + fuse + 1));
    }
}

// Round 9
// 466.704 us; speedup vs baseline: 2.0632x; 1.0486x over previous
//
#include <hip/hip_runtime.h>
#include <hip/hip_fp16.h>
#include <math.h>

#define NUM_BASIS 8
#define SQRT3 1.7320508075688772f
#define SQRT2 1.4142135623730951f
#define INV_SQRT_DEG 0.17677669529663687f   // 1/sqrt(32)
#define PI_F 3.14159265358979323846f

typedef _Float16 half8 __attribute__((ext_vector_type(8)));
typedef float float4v __attribute__((ext_vector_type(4)));

__device__ __forceinline__ float sigmoidf_(float x) { return 1.0f / (1.0f + __expf(-x)); }
__device__ __forceinline__ float siluf_(float x) { return x * sigmoidf_(x); }

__device__ __forceinline__ void unp2(unsigned u, float& a, float& b) {
    __half2 h = *reinterpret_cast<__half2*>(&u);
    float2 f = __half22float2(h);
    a = f.x; b = f.y;
}
__device__ __forceinline__ unsigned pk2(float a, float b) {
    __half2 h = __floats2half2_rn(a, b);
    return *reinterpret_cast<unsigned*>(&h);
}

// ---------------------------------------------------------------------------
// CSR build: degree count (4 edges/thread) -> scan (fused with weight prep)
// ---------------------------------------------------------------------------
__global__ __launch_bounds__(256) void count_deg(
    const int* __restrict__ dst, int* __restrict__ deg, int E)
{
    int base = (blockIdx.x * blockDim.x + threadIdx.x) * 4;
    if (base + 3 < E) {
        int4 d4 = *(const int4*)(dst + base);
        atomicAdd(&deg[d4.x], 1);
        atomicAdd(&deg[d4.y], 1);
        atomicAdd(&deg[d4.z], 1);
        atomicAdd(&deg[d4.w], 1);
    } else {
        for (int e = base; e < E; e++) atomicAdd(&deg[dst[e]], 1);
    }
}

// R24: scan (block 0) fused with weight prep (blocks >= 1).
__global__ __launch_bounds__(1024) void scan_prep(
    const int* __restrict__ deg, int* __restrict__ cursor, int N,
    const float* __restrict__ W2, _Float16* __restrict__ w2f,
    const float* __restrict__ Wg, const float* __restrict__ Ws,
    const float* __restrict__ Wv, _Float16* __restrict__ wgtf,
    const float* __restrict__ Wl1, const float* __restrict__ Wl2,
    float* __restrict__ wl12)
{
    if (blockIdx.x != 0) {
        int idx = ((int)blockIdx.x - 1) * 1024 + (int)threadIdx.x;
        if (idx < 64) {
            float a = 0.f;
            #pragma unroll
            for (int j = 0; j < 16; j++) a = fmaf(Wl1[idx*16 + j], Wl2[j], a);
            wl12[idx] = a;
        }
        if (idx < 3 * 20480) {
            int L  = idx / 20480;
            int r  = idx % 20480;
            int cg = r / 5120;
            int r2 = r % 5120;
            int p  = r2 / 1024;
            int r3 = r2 % 1024;
            int kh = r3 / 512;
            int r4 = r3 % 512;
            int lane = r4 / 8;
            int j  = r4 % 8;
            int k = kh*32 + (lane >> 4)*8 + j;
            int n = p*64 + cg*16 + (lane & 15);
            float val = W2[(size_t)L*20480 + k*320 + n];
            if (p == 1)      val *= 0.5773502691896258f;   // 1/sqrt(3)
            else if (p == 4) val *= 0.7071067811865476f;   // 1/sqrt(2)
            w2f[idx] = (_Float16)val;
        } else if (idx < 3*20480 + 3*3*4096) {
            int idx2 = idx - 3*20480;
            int L   = idx2 / 12288;
            int rem = idx2 % 12288;
            int mat = rem / 4096;
            int r2  = rem % 4096;
            int cg  = r2 / 1024;
            int r3  = r2 % 1024;
            int kh  = r3 / 512;
            int r4  = r3 % 512;
            int lane = r4 / 8;
            int j   = r4 % 8;
            int k = kh*32 + (lane >> 4)*8 + j;
            int n = cg*16 + (lane & 15);
            const float* src = (mat == 0) ? Wg : (mat == 1) ? Ws : Wv;
            wgtf[idx2] = (_Float16)src[(size_t)L*4096 + k*64 + n];
        }
        return;
    }

    __shared__ int wsum[16];
    __shared__ int carry_s, tot_s;
    int tid = threadIdx.x;
    int wid = tid >> 6, lane = tid & 63;
    if (tid == 0) carry_s = 0;
    __syncthreads();
    for (int base = 0; base < N; base += 16384) {
        int i0 = base + tid * 16;
        int v[16];
        int sum = 0;
        #pragma unroll
        for (int k = 0; k < 16; k++) {
            int i = i0 + k;
            v[k] = (i < N) ? deg[i] : 0;
            sum += v[k];
        }
        int incl = sum;
        #pragma unroll
        for (int off = 1; off < 64; off <<= 1) {
            int t = __shfl_up(incl, off);
            if (lane >= off) incl += t;
        }
        if (lane == 63) wsum[wid] = incl;
        __syncthreads();
        if (wid == 0 && lane < 16) {
            int wv = wsum[lane];
            int wincl = wv;
            #pragma unroll
            for (int off = 1; off < 16; off <<= 1) {
                int t = __shfl_up(wincl, off);
                if (lane >= off) wincl += t;
            }
            wsum[lane] = wincl - wv;
            if (lane == 15) tot_s = wincl;
        }
        __syncthreads();
        int carry = carry_s;
        int run = carry + wsum[wid] + incl - sum;   // exclusive prefix at i0
        #pragma unroll
        for (int k = 0; k < 16; k++) {
            int i = i0 + k;
            if (i < N) cursor[i] = run;
            run += v[k];
        }
        __syncthreads();
        if (tid == 0) carry_s = carry + tot_s;
        __syncthreads();
    }
}

// Per-edge geometry + radial embedding, scattered directly into CSR slots.
// emb stored f16x8 (16B), y14 stored f16x4 (8B).
__global__ __launch_bounds__(256) void edge_pre_scatter(
    const float* __restrict__ pos, const int* __restrict__ src,
    const int* __restrict__ dst, const float* __restrict__ cs,
    const float* __restrict__ cell, const int* __restrict__ img,
    int* __restrict__ cursor, _Float16* __restrict__ emb,
    uint2* __restrict__ y14, int2* __restrict__ sdp, int E)
{
    int e = blockIdx.x * blockDim.x + threadIdx.x;
    if (e >= E) return;
    int si = src[e], di = dst[e];
    int slot = atomicAdd(&cursor[di], 1);
    sdp[slot] = make_int2(si, di);
    float vx = pos[di*3+0] - pos[si*3+0];
    float vy = pos[di*3+1] - pos[si*3+1];
    float vz = pos[di*3+2] - pos[si*3+2];
    float c0 = cs[(size_t)e*3+0], c1 = cs[(size_t)e*3+1], c2 = cs[(size_t)e*3+2];
    const float* M = cell + (size_t)img[si] * 9;
    vx += c0*M[0] + c1*M[3] + c2*M[6];
    vy += c0*M[1] + c1*M[4] + c2*M[7];
    vz += c0*M[2] + c1*M[5] + c2*M[8];
    float r  = sqrtf(vx*vx + vy*vy + vz*vz);
    float rs = fmaxf(r, 1e-9f);
    float inv = 1.0f / rs;
    uint2 yv;
    yv.x = pk2(SQRT3*vx*inv, SQRT3*vy*inv);
    yv.y = pk2(SQRT3*vz*inv, 0.f);
    y14[slot] = yv;
    // polynomial cutoff p=6: 1 - 28 x^6 + 48 x^7 - 21 x^8 (0 for x>=1)
    float x = r * (1.0f / 5.0f);
    float x2 = x*x, x6 = x2*x2*x2;
    float fc = 1.0f - 28.0f*x6 + 48.0f*x6*x - 21.0f*x6*x2;
    if (x >= 1.0f) fc = 0.0f;
    float pre = sqrtf(2.0f / 5.0f) * inv * fc;
    float t = PI_F * rs * (1.0f / 5.0f);
    half8 ev;
    #pragma unroll
    for (int n = 1; n <= NUM_BASIS; n++)
        ev[n-1] = (_Float16)(pre * __sinf((float)n * t));
    *(half8*)(emb + (size_t)slot*NUM_BASIS) = ev;
}

// ---------------------------------------------------------------------------
// MLP1 precompute body (R23 grid-strided, weights in registers). Standalone
// kernel for L0; the same body runs in tail blocks of node_update (R24).
// ---------------------------------------------------------------------------
__device__ __forceinline__ void mlp1_pre_body(
    const _Float16* __restrict__ emb, const float* __restrict__ W1,
    const float* __restrict__ B1, _Float16* __restrict__ hA, int E,
    int g, int nthreads)
{
    int kb   = (g & 7) * 8;
    int es   = g >> 3;
    int estr = nthreads >> 3;
    float wv[8][8];
    #pragma unroll
    for (int jj = 0; jj < 8; jj++) {
        float4 a = *(const float4*)(W1 + jj*64 + kb);
        float4 b = *(const float4*)(W1 + jj*64 + kb + 4);
        wv[jj][0]=a.x; wv[jj][1]=a.y; wv[jj][2]=a.z; wv[jj][3]=a.w;
        wv[jj][4]=b.x; wv[jj][5]=b.y; wv[jj][6]=b.z; wv[jj][7]=b.w;
    }
    float bv[8];
    {
        float4 a = *(const float4*)(B1 + kb);
        float4 b = *(const float4*)(B1 + kb + 4);
        bv[0]=a.x; bv[1]=a.y; bv[2]=a.z; bv[3]=a.w;
        bv[4]=b.x; bv[5]=b.y; bv[6]=b.z; bv[7]=b.w;
    }
    for (int e = es; e < E; e += estr) {
        half8 ev = *(const half8*)(emb + (size_t)e*8);
        float hv[8];
        #pragma unroll
        for (int j = 0; j < 8; j++) hv[j] = bv[j];
        #pragma unroll
        for (int jj = 0; jj < 8; jj++) {
            float em = (float)ev[jj];
            #pragma unroll
            for (int j = 0; j < 8; j++)
                hv[j] = fmaf(em, wv[jj][j], hv[j]);
        }
        half8 out;
        #pragma unroll
        for (int j = 0; j < 8; j++) out[j] = (_Float16)siluf_(hv[j]);
        *(half8*)(hA + (size_t)e*64 + kb) = out;
    }
}

__global__ __launch_bounds__(256) void mlp1_pre(
    const _Float16* __restrict__ emb, const float* __restrict__ W1,
    const float* __restrict__ B1, _Float16* __restrict__ hA, int E)
{
    int g = blockIdx.x * blockDim.x + threadIdx.x;
    mlp1_pre_body(emb, W1, B1, hA, E, g, gridDim.x * blockDim.x);
}

// ---------------------------------------------------------------------------
// A-frag MLP1 (fallback when workspace can't hold hA)
// ---------------------------------------------------------------------------
__device__ __forceinline__ void mlp1_afrag(
    const _Float16* __restrict__ emb, const float* __restrict__ W1,
    const float* __restrict__ B1, int eA, int q, half8 afrag[2])
{
    half8 ev = *(const half8*)(emb + (size_t)eA*8);
    float em[8];
    #pragma unroll
    for (int j = 0; j < 8; j++) em[j] = (float)ev[j];
    #pragma unroll
    for (int kh = 0; kh < 2; kh++) {
        int kb = kh*32 + q*8;
        float hv[8];
        float4 b0 = *(const float4*)(B1 + kb);
        float4 b1 = *(const float4*)(B1 + kb + 4);
        hv[0]=b0.x; hv[1]=b0.y; hv[2]=b0.z; hv[3]=b0.w;
        hv[4]=b1.x; hv[5]=b1.y; hv[6]=b1.z; hv[7]=b1.w;
        #pragma unroll
        for (int jj = 0; jj < 8; jj++) {
            float4 wa = *(const float4*)(W1 + jj*64 + kb);
            float4 wb = *(const float4*)(W1 + jj*64 + kb + 4);
            hv[0] = fmaf(em[jj], wa.x, hv[0]);
            hv[1] = fmaf(em[jj], wa.y, hv[1]);
            hv[2] = fmaf(em[jj], wa.z, hv[2]);
            hv[3] = fmaf(em[jj], wa.w, hv[3]);
            hv[4] = fmaf(em[jj], wb.x, hv[4]);
            hv[5] = fmaf(em[jj], wb.y, hv[5]);
            hv[6] = fmaf(em[jj], wb.z, hv[6]);
            hv[7] = fmaf(em[jj], wb.w, hv[7]);
        }
        #pragma unroll
        for (int j = 0; j < 8; j++)
            afrag[kh][j] = (_Float16)siluf_(hv[j]);
    }
}

// R28: revert to R25's LDS-staged structure (R27's global-direct B-frags
// thrashed L1: 40KB > 32KB L1 -> L2 round-trips, 79->95us). New lever:
// WAVE-PAIR cg-split in edge_msg — two waves per 16-edge tile, wave h owns
// cg {2h,2h+1}. Staging SHARED in the 512-thread block (40 KB staged once,
// ONE barrier, no time-multiplex restage). Duplication per wave is only
// ~8 metadata + 2 hA loads (MLP1 is precomputed since R22) vs R20's +35%.
// Halves the per-wave serial chain (20 MFMA, 2 carry chains, 1 pf gather),
// doubles independent chains for latency hiding.
// ---------------------------------------------------------------------------
// Layer-0 edge kernel (R25 form): v == 0 -> only w1/w3 paths, 16 KB LDS.
// ---------------------------------------------------------------------------
template<bool PRE>
__global__ __launch_bounds__(256) void edge_msg_mfma_l0(
    const _Float16* __restrict__ emb, const _Float16* __restrict__ hA,
    const uint2* __restrict__ y14, const int2* __restrict__ sdp,
    const int* __restrict__ type, const float* __restrict__ wlin,
    const float* __restrict__ W1, const float* __restrict__ B1,
    const _Float16* __restrict__ w2f,
    float* __restrict__ aggs, float* __restrict__ aggx,
    float* __restrict__ aggy, float* __restrict__ aggz, int E)
{
    __shared__ _Float16 w2s[8192];   // 16 KB: [cg][pp in {p0,p2}][kh][512]
    {
        half8* dstv = (half8*)w2s;
        const half8* srcv = (const half8*)w2f;
        #pragma unroll
        for (int k = 0; k < 4; k++) {
            int t  = threadIdx.x + k*256;
            int cg = t >> 8;
            int r  = t & 255;
            int pp = r >> 7;          // 0 -> path 0 (w1), 1 -> path 2 (w3)
            int rk = r & 127;         // kh*64 + lane
            dstv[t] = srcv[cg*640 + pp*256 + rk];
        }
    }
    __syncthreads();

    int wave  = (blockIdx.x * blockDim.x + threadIdx.x) >> 6;
    int lane  = threadIdx.x & 63;
    int wbase = wave * 16;
    if (wbase >= E) return;
    int q   = lane >> 4;
    int col = lane & 15;

    half8 afrag[2];
    if (PRE) {
        const _Float16* hp = hA + (size_t)(wbase + col)*64 + q*8;
        afrag[0] = *(const half8*)(hp);
        afrag[1] = *(const half8*)(hp + 32);
    }

    int eb = wbase + q*4;
    int d[4], tt[4];
    float y1x[4], y1y[4], y1z[4];
    #pragma unroll
    for (int r = 0; r < 4; r++) {
        int2 sv = sdp[eb + r];
        tt[r] = type[sv.x];
        d[r]  = sv.y;
        uint2 yv = y14[eb + r];
        float dummy;
        unp2(yv.x, y1x[r], y1y[r]);
        unp2(yv.y, y1z[r], dummy);
    }

    if (!PRE) mlp1_afrag(emb, W1, B1, wbase + col, q, afrag);

    int dfirst = __shfl(d[0], 0);
    bool uni = __all(d[3] == dfirst);     // dst-sorted -> all 16 equal

    int dnq = __shfl_down(d[0], 16);      // next quad's first dst
    int nd3 = (q == 3) ? -1 : dnq;        // q3 reg3: forced tail
    int df = d[0], dl = d[3];
    bool U = (df == dl);
    int dlp = __shfl_up(dl, 16);
    bool link = (q > 0) && (dlp == df);

    #pragma unroll
    for (int cg = 0; cg < 4; cg++) {
        float4v a1 = {0,0,0,0}, a3 = {0,0,0,0};
        const _Float16* wbp = w2s + ((size_t)cg*2048) + (size_t)lane*8;
        {
            half8 b10 = *(const half8*)(wbp + 0*512);
            half8 b11 = *(const half8*)(wbp + 1*512);
            half8 b30 = *(const half8*)(wbp + 2*512);
            half8 b31 = *(const half8*)(wbp + 3*512);
            a1 = __builtin_amdgcn_mfma_f32_16x16x32_f16(afrag[0], b10, a1, 0, 0, 0);
            a1 = __builtin_amdgcn_mfma_f32_16x16x32_f16(afrag[1], b11, a1, 0, 0, 0);
            a3 = __builtin_amdgcn_mfma_f32_16x16x32_f16(afrag[0], b30, a3, 0, 0, 0);
            a3 = __builtin_amdgcn_mfma_f32_16x16x32_f16(afrag[1], b31, a3, 0, 0, 0);
        }
        int c = cg*16 + col;

        float ms[4], mx[4], my[4], mz[4];
        #pragma unroll
        for (int r = 0; r < 4; r++) {
            float s = wlin[tt[r]*64 + c];
            float w3s = a3[r] * s;
            ms[r] = a1[r] * s;
            mx[r] = w3s * y1x[r];
            my[r] = w3s * y1y[r];
            mz[r] = w3s * y1z[r];
        }

        if (uni) {
            float fs = (ms[0]+ms[1]) + (ms[2]+ms[3]);
            float fx = (mx[0]+mx[1]) + (mx[2]+mx[3]);
            float fy = (my[0]+my[1]) + (my[2]+my[3]);
            float fz = (mz[0]+mz[1]) + (mz[2]+mz[3]);
            fs += __shfl_xor(fs, 16); fx += __shfl_xor(fx, 16);
            fy += __shfl_xor(fy, 16); fz += __shfl_xor(fz, 16);
            fs += __shfl_xor(fs, 32); fx += __shfl_xor(fx, 32);
            fy += __shfl_xor(fy, 32); fz += __shfl_xor(fz, 32);
            if (q == 0) {
                size_t ai = (size_t)d[0]*64 + c;
                atomicAdd(aggs + ai, fs);
                atomicAdd(aggx + ai, fx);
                atomicAdd(aggy + ai, fy);
                atomicAdd(aggz + ai, fz);
            }
            continue;
        }

        #pragma unroll
        for (int r = 1; r < 4; r++) {
            if (d[r] == d[r-1]) {
                ms[r] += ms[r-1]; mx[r] += mx[r-1];
                my[r] += my[r-1]; mz[r] += mz[r-1];
            }
        }
        // cross-quad carry (chains up to 4 quads -> 3 iterations)
        float Cs = 0.f, Cx = 0.f, Cy = 0.f, Cz = 0.f;
        #pragma unroll
        for (int it = 0; it < 3; it++) {
            float es = ms[3] + (U ? Cs : 0.f);
            float ex = mx[3] + (U ? Cx : 0.f);
            float ey = my[3] + (U ? Cy : 0.f);
            float ez = mz[3] + (U ? Cz : 0.f);
            float ts = __shfl_up(es, 16);
            float tx = __shfl_up(ex, 16);
            float ty = __shfl_up(ey, 16);
            float tz = __shfl_up(ez, 16);
            Cs = link ? ts : 0.f; Cx = link ? tx : 0.f;
            Cy = link ? ty : 0.f; Cz = link ? tz : 0.f;
        }
        bool hr = true;
        #pragma unroll
        for (int r = 0; r < 4; r++) {
            if (r > 0) hr = hr && (d[r] == d[r-1]);
            float fs = ms[r] + (hr ? Cs : 0.f);
            float fx = mx[r] + (hr ? Cx : 0.f);
            float fy = my[r] + (hr ? Cy : 0.f);
            float fz = mz[r] + (hr ? Cz : 0.f);
            int ndx = (r < 3) ? d[r+1] : nd3;
            if (ndx != d[r] && d[r] >= 0) {
                size_t ai = (size_t)d[r]*64 + c;
                atomicAdd(aggs + ai, fs);
                atomicAdd(aggx + ai, fx);
                atomicAdd(aggy + ai, fy);
                atomicAdd(aggz + ai, fz);
            }
        }
    }
}

// ---------------------------------------------------------------------------
// Process two cg's (one half) of the general edge kernel from staged LDS.
// ---------------------------------------------------------------------------
__device__ __forceinline__ void process_half(
    const _Float16* __restrict__ w2h, const half8 afrag[2],
    const uint2 pf[4][2], const int d[4], int nd3, bool U, bool link,
    bool uni, const float* y1x, const float* y1y, const float* y1z,
    int cgh, int col,
    float* __restrict__ aggs, float* __restrict__ aggx,
    float* __restrict__ aggy, float* __restrict__ aggz)
{
    int lane = threadIdx.x & 63;
    int q = lane >> 4;
    #pragma unroll
    for (int cgl = 0; cgl < 2; cgl++) {
        float4v acc[5];
        #pragma unroll
        for (int p = 0; p < 5; p++) acc[p] = (float4v){0.f, 0.f, 0.f, 0.f};
        const _Float16* wbp = w2h + ((size_t)cgl*5120) + (size_t)lane*8;
        #pragma unroll
        for (int p = 0; p < 5; p++) {
            half8 bf0 = *(const half8*)(wbp + ((size_t)(p*2 + 0))*512);
            half8 bf1 = *(const half8*)(wbp + ((size_t)(p*2 + 1))*512);
            acc[p] = __builtin_amdgcn_mfma_f32_16x16x32_f16(afrag[0], bf0, acc[p], 0, 0, 0);
            acc[p] = __builtin_amdgcn_mfma_f32_16x16x32_f16(afrag[1], bf1, acc[p], 0, 0, 0);
        }
        int c = (cgh*2 + cgl)*16 + col;

        float ms[4], mx[4], my[4], mz[4];
        #pragma unroll
        for (int r = 0; r < 4; r++) {
            float fsx, fvx, fvy, fvz;
            unp2(pf[r][cgl].x, fsx, fvx);
            unp2(pf[r][cgl].y, fvy, fvz);
            float yx = y1x[r], yy = y1y[r], yz = y1z[r];
            float w1 = acc[0][r], w2 = acc[1][r], w3 = acc[2][r];
            float w4 = acc[3][r], w5 = acc[4][r];
            float vdoty = fvx*yx + fvy*yy + fvz*yz;
            ms[r] = fmaf(w1, fsx, w2*vdoty);           // w2 pre-scaled 1/sqrt3
            float w3s = w3*fsx;
            float cx = fvy*yz - fvz*yy;
            float cy = fvz*yx - fvx*yz;
            float cz = fvx*yy - fvy*yx;
            mx[r] = fmaf(w3s, yx, fmaf(w4, fvx, w5*cx));  // w5 pre-scaled 1/sqrt2
            my[r] = fmaf(w3s, yy, fmaf(w4, fvy, w5*cy));
            mz[r] = fmaf(w3s, yz, fmaf(w4, fvz, w5*cz));
        }

        if (uni) {
            float fs = (ms[0]+ms[1]) + (ms[2]+ms[3]);
            float fx = (mx[0]+mx[1]) + (mx[2]+mx[3]);
            float fy = (my[0]+my[1]) + (my[2]+my[3]);
            float fz = (mz[0]+mz[1]) + (mz[2]+mz[3]);
            fs += __shfl_xor(fs, 16); fx += __shfl_xor(fx, 16);
            fy += __shfl_xor(fy, 16); fz += __shfl_xor(fz, 16);
            fs += __shfl_xor(fs, 32); fx += __shfl_xor(fx, 32);
            fy += __shfl_xor(fy, 32); fz += __shfl_xor(fz, 32);
            if (q == 0) {
                size_t ai = (size_t)d[0]*64 + c;
                atomicAdd(aggs + ai, fs);
                atomicAdd(aggx + ai, fx);
                atomicAdd(aggy + ai, fy);
                atomicAdd(aggz + ai, fz);
            }
            continue;
        }

        #pragma unroll
        for (int r = 1; r < 4; r++) {
            if (d[r] == d[r-1]) {
                ms[r] += ms[r-1]; mx[r] += mx[r-1];
                my[r] += my[r-1]; mz[r] += mz[r-1];
            }
        }
        float Cs = 0.f, Cx = 0.f, Cy = 0.f, Cz = 0.f;
        #pragma unroll
        for (int it = 0; it < 3; it++) {
            float es = ms[3] + (U ? Cs : 0.f);
            float ex = mx[3] + (U ? Cx : 0.f);
            float ey = my[3] + (U ? Cy : 0.f);
            float ez = mz[3] + (U ? Cz : 0.f);
            float ts = __shfl_up(es, 16);
            float tx = __shfl_up(ex, 16);
            float ty = __shfl_up(ey, 16);
            float tz = __shfl_up(ez, 16);
            Cs = link ? ts : 0.f; Cx = link ? tx : 0.f;
            Cy = link ? ty : 0.f; Cz = link ? tz : 0.f;
        }
        bool hr = true;
        #pragma unroll
        for (int r = 0; r < 4; r++) {
            if (r > 0) hr = hr && (d[r] == d[r-1]);
            float fs = ms[r] + (hr ? Cs : 0.f);
            float fx = mx[r] + (hr ? Cx : 0.f);
            float fy = my[r] + (hr ? Cy : 0.f);
            float fz = mz[r] + (hr ? Cz : 0.f);
            int ndx = (r < 3) ? d[r+1] : nd3;
            if (ndx != d[r] && d[r] >= 0) {
                size_t ai = (size_t)d[r]*64 + c;
                atomicAdd(aggs + ai, fs);
                atomicAdd(aggx + ai, fx);
                atomicAdd(aggy + ai, fy);
                atomicAdd(aggz + ai, fz);
            }
        }
    }
}

// ---------------------------------------------------------------------------
// General MFMA edge kernel (layers >= 1), R28 wave-pair split:
// 512-thread block = 8 waves = 4 tiles x 2 waves. Wave h of a pair owns
// cg {2h, 2h+1}. Full 40 KB B-frag staged once, ONE barrier. Each wave
// does ONE pf gather (its 32 cols), 20 MFMA, 2 carry/flush chains.
// ---------------------------------------------------------------------------
template<bool PRE>
__global__ __launch_bounds__(512) void edge_msg_mfma(
    const _Float16* __restrict__ emb, const _Float16* __restrict__ hA,
    const uint2* __restrict__ y14, const int2* __restrict__ sdp,
    const uint2* __restrict__ nf,
    const float* __restrict__ W1, const float* __restrict__ B1,
    const _Float16* __restrict__ w2f,
    float* __restrict__ aggs, float* __restrict__ aggx,
    float* __restrict__ aggy, float* __restrict__ aggz, int E)
{
    __shared__ _Float16 w2s[20480];   // 40 KB, full layer
    {
        half8* dstv = (half8*)w2s;
        const half8* srcv = (const half8*)w2f;
        #pragma unroll
        for (int k = 0; k < 5; k++)
            dstv[threadIdx.x + k*512] = srcv[threadIdx.x + k*512];
    }

    int widx = (int)threadIdx.x >> 6;     // 0..7
    int pair = widx >> 1;                 // tile within block: 0..3
    int h    = widx & 1;                  // cg half: {0,1} or {2,3}
    int lane = threadIdx.x & 63;
    int wave  = blockIdx.x * 4 + pair;
    int wbase = wave * 16;
    bool live = wbase < E;
    int wb2   = live ? wbase : 0;
    int q   = lane >> 4;
    int col = lane & 15;

    half8 afrag[2];
    if (PRE) {
        const _Float16* hp = hA + (size_t)(wb2 + col)*64 + q*8;
        afrag[0] = *(const half8*)(hp);
        afrag[1] = *(const half8*)(hp + 32);
    }

    int eb = wb2 + q*4;
    int d[4], si[4];
    float y1x[4], y1y[4], y1z[4];
    #pragma unroll
    for (int r = 0; r < 4; r++) {
        int2 sv = sdp[eb + r];
        si[r] = sv.x;
        d[r]  = sv.y;
        uint2 yv = y14[eb + r];
        float dummy;
        unp2(yv.x, y1x[r], y1y[r]);
        unp2(yv.y, y1z[r], dummy);
    }

    // this wave's pf gather: cols h*32 + {col, col+16}
    uint2 pf[4][2];
    #pragma unroll
    for (int r = 0; r < 4; r++) {
        size_t nb = (size_t)si[r] * 64 + h*32 + col;
        pf[r][0] = nf[nb];
        pf[r][1] = nf[nb + 16];
    }

    if (!PRE) mlp1_afrag(emb, W1, B1, wb2 + col, q, afrag);

    int dfirst = __shfl(d[0], 0);
    bool uni = __all(d[3] == dfirst);     // dst-sorted -> all 16 equal

    int dnq = __shfl_down(d[0], 16);
    int nd3 = (q == 3) ? -1 : dnq;
    int df = d[0], dl = d[3];
    bool U = (df == dl);
    int dlp = __shfl_up(dl, 16);
    bool link = (q > 0) && (dlp == df);

    __syncthreads();   // staging complete (issued above, before all loads use)
    if (!live) return;

    process_half(w2s + (size_t)h*10240, afrag, pf, d, nd3, U, link, uni,
                 y1x, y1y, y1z, h, col, aggs, aggx, aggy, aggz);
}

// ---------------------------------------------------------------------------
// MFMA node update: one wave per 16 nodes (R12). wgtf staged in LDS.
// first=1 (L0): residual s from wlin[type], v = 0. Epilogue zeroes agg in
// place; fused energy projection on last layer.
// R24: tail blocks (blockIdx >= nb_node) run mlp1_pre for the NEXT layer.
// ---------------------------------------------------------------------------
__global__ __launch_bounds__(256) void node_update_mfma(
    uint2* __restrict__ nf,
    float* __restrict__ aggs, float* __restrict__ aggx,
    float* __restrict__ aggy, float* __restrict__ aggz,
    const _Float16* __restrict__ wgtf,
    const int* __restrict__ type, const float* __restrict__ wlin,
    const float* __restrict__ wl12,
    float* __restrict__ out, int first, int do_out, int N,
    const _Float16* __restrict__ emb, const float* __restrict__ W1n,
    const float* __restrict__ B1n, _Float16* __restrict__ hA, int E,
    int nb_node)
{
    if ((int)blockIdx.x >= nb_node) {
        int g = ((int)blockIdx.x - nb_node) * 256 + (int)threadIdx.x;
        mlp1_pre_body(emb, W1n, B1n, hA, E, g,
                      ((int)gridDim.x - nb_node) * 256);
        return;
    }

    __shared__ _Float16 wgs[12288];   // 24.6 KB
    {
        half8* dstv = (half8*)wgs;
        const half8* srcv = (const half8*)wgtf;
        #pragma unroll
        for (int k = 0; k < 6; k++)
            dstv[threadIdx.x + k*256] = srcv[threadIdx.x + k*256];
    }

    int wave  = (blockIdx.x * blockDim.x + threadIdx.x) >> 6;
    int lane  = threadIdx.x & 63;
    int wbase = wave * 16;
    bool active = wbase < N;
    int q = lane >> 4, col = lane & 15;

    int nodeA = active ? (wbase + col) : 0;
    if (nodeA >= N) nodeA = N - 1;
    size_t nb = (size_t)nodeA * 64 + q * 8;
    half8 af0[2], af1[2], af2[2], af3[2];
    #pragma unroll
    for (int kh = 0; kh < 2; kh++) {
        const float* p0 = aggs + nb + kh*32;
        const float* p1 = aggx + nb + kh*32;
        const float* p2 = aggy + nb + kh*32;
        const float* p3 = aggz + nb + kh*32;
        float4 a0 = *(const float4*)p0, b0 = *(const float4*)(p0+4);
        float4 a1 = *(const float4*)p1, b1 = *(const float4*)(p1+4);
        float4 a2 = *(const float4*)p2, b2 = *(const float4*)(p2+4);
        float4 a3 = *(const float4*)p3, b3 = *(const float4*)(p3+4);
        af0[kh][0]=(_Float16)(a0.x*INV_SQRT_DEG); af0[kh][1]=(_Float16)(a0.y*INV_SQRT_DEG);
        af0[kh][2]=(_Float16)(a0.z*INV_SQRT_DEG); af0[kh][3]=(_Float16)(a0.w*INV_SQRT_DEG);
        af0[kh][4]=(_Float16)(b0.x*INV_SQRT_DEG); af0[kh][5]=(_Float16)(b0.y*INV_SQRT_DEG);
        af0[kh][6]=(_Float16)(b0.z*INV_SQRT_DEG); af0[kh][7]=(_Float16)(b0.w*INV_SQRT_DEG);
        af1[kh][0]=(_Float16)(a1.x*INV_SQRT_DEG); af1[kh][1]=(_Float16)(a1.y*INV_SQRT_DEG);
        af1[kh][2]=(_Float16)(a1.z*INV_SQRT_DEG); af1[kh][3]=(_Float16)(a1.w*INV_SQRT_DEG);
        af1[kh][4]=(_Float16)(b1.x*INV_SQRT_DEG); af1[kh][5]=(_Float16)(b1.y*INV_SQRT_DEG);
        af1[kh][6]=(_Float16)(b1.z*INV_SQRT_DEG); af1[kh][7]=(_Float16)(b1.w*INV_SQRT_DEG);
        af2[kh][0]=(_Float16)(a2.x*INV_SQRT_DEG); af2[kh][1]=(_Float16)(a2.y*INV_SQRT_DEG);
        af2[kh][2]=(_Float16)(a2.z*INV_SQRT_DEG); af2[kh][3]=(_Float16)(a2.w*INV_SQRT_DEG);
        af2[kh][4]=(_Float16)(b2.x*INV_SQRT_DEG); af2[kh][5]=(_Float16)(b2.y*INV_SQRT_DEG);
        af2[kh][6]=(_Float16)(b2.z*INV_SQRT_DEG); af2[kh][7]=(_Float16)(b2.w*INV_SQRT_DEG);
        af3[kh][0]=(_Float16)(a3.x*INV_SQRT_DEG); af3[kh][1]=(_Float16)(a3.y*INV_SQRT_DEG);
        af3[kh][2]=(_Float16)(a3.z*INV_SQRT_DEG); af3[kh][3]=(_Float16)(a3.w*INV_SQRT_DEG);
        af3[kh][4]=(_Float16)(b3.x*INV_SQRT_DEG); af3[kh][5]=(_Float16)(b3.y*INV_SQRT_DEG);
        af3[kh][6]=(_Float16)(b3.z*INV_SQRT_DEG); af3[kh][7]=(_Float16)(b3.w*INV_SQRT_DEG);
    }

    int tt[4];
    #pragma unroll
    for (int r = 0; r < 4; r++) {
        int nd = wbase + q*4 + r;
        tt[r] = type[(active && nd < N) ? nd : 0];
    }

    __syncthreads();   // wgs staged; all waves arrive

    float epart[4] = {0.f, 0.f, 0.f, 0.f};

    #pragma unroll
    for (int cg = 0; cg < 4; cg++) {
        const _Float16* bp = wgs + (size_t)lane * 8;
        half8 bg0 = *(const half8*)(bp + ((size_t)((0*4 + cg)*2 + 0))*512);
        half8 bg1 = *(const half8*)(bp + ((size_t)((0*4 + cg)*2 + 1))*512);
        half8 bs0 = *(const half8*)(bp + ((size_t)((1*4 + cg)*2 + 0))*512);
        half8 bs1 = *(const half8*)(bp + ((size_t)((1*4 + cg)*2 + 1))*512);
        half8 bv0 = *(const half8*)(bp + ((size_t)((2*4 + cg)*2 + 0))*512);
        half8 bv1 = *(const half8*)(bp + ((size_t)((2*4 + cg)*2 + 1))*512);
        float4v ag = {0,0,0,0}, as = {0,0,0,0};
        float4v ox = {0,0,0,0}, oy = {0,0,0,0}, oz = {0,0,0,0};
        ag = __builtin_amdgcn_mfma_f32_16x16x32_f16(af0[0], bg0, ag, 0, 0, 0);
        ag = __builtin_amdgcn_mfma_f32_16x16x32_f16(af0[1], bg1, ag, 0, 0, 0);
        as = __builtin_amdgcn_mfma_f32_16x16x32_f16(af0[0], bs0, as, 0, 0, 0);
        as = __builtin_amdgcn_mfma_f32_16x16x32_f16(af0[1], bs1, as, 0, 0, 0);
        ox = __builtin_amdgcn_mfma_f32_16x16x32_f16(af1[0], bv0, ox, 0, 0, 0);
        ox = __builtin_amdgcn_mfma_f32_16x16x32_f16(af1[1], bv1, ox, 0, 0, 0);
        oy = __builtin_amdgcn_mfma_f32_16x16x32_f16(af2[0], bv0, oy, 0, 0, 0);
        oy = __builtin_amdgcn_mfma_f32_16x16x32_f16(af2[1], bv1, oy, 0, 0, 0);
        oz = __builtin_amdgcn_mfma_f32_16x16x32_f16(af3[0], bv0, oz, 0, 0, 0);
        oz = __builtin_amdgcn_mfma_f32_16x16x32_f16(af3[1], bv1, oz, 0, 0, 0);

        if (!active) continue;
        int c = cg*16 + col;
        float wlc = wl12[c];
        #pragma unroll
        for (int r = 0; r < 4; r++) {
            int nd = wbase + q*4 + r;
            bool wr = nd < N;
            size_t ni = (size_t)nd*64 + c;
            float sx, vx, vy, vz;
            if (first) {
                sx = wlin[tt[r]*64 + c];
                vx = 0.f; vy = 0.f; vz = 0.f;
            } else {
                uint2 cur = nf[wr ? ni : 0];
                unp2(cur.x, sx, vx);
                unp2(cur.y, vy, vz);
            }
            float gate = sigmoidf_(ag[r]);
            sx += siluf_(as[r]);
            vx += ox[r] * gate;
            vy += oy[r] * gate;
            vz += oz[r] * gate;
            if (wr) {
                uint2 nv;
                nv.x = pk2(sx, vx);
                nv.y = pk2(vy, vz);
                nf[ni] = nv;
                aggs[ni] = 0.f;   // in-place zero replaces per-layer memset
                aggx[ni] = 0.f;
                aggy[ni] = 0.f;
                aggz[ni] = 0.f;
                epart[r] = fmaf(sx, wlc, epart[r]);
            }
        }
    }
    if (do_out && active) {
        #pragma unroll
        for (int r = 0; r < 4; r++) {
            float e = epart[r];
            e += __shfl_xor(e, 1);
            e += __shfl_xor(e, 2);
            e += __shfl_xor(e, 4);
            e += __shfl_xor(e, 8);
            int nd = wbase + q*4 + r;
            if (col == 0 && nd < N) out[nd] = e;
        }
    }
}

extern "C" void kernel_launch(void* const* d_in, const int* in_sizes, int n_in,
                              void* d_out, int out_size, void* d_ws, size_t ws_size,
                              hipStream_t stream)
{
    const int*   atom_type = (const int*)  d_in[0];
    const float* pos       = (const float*)d_in[1];
    const int*   src       = (const int*)  d_in[2];
    const int*   dst       = (const int*)  d_in[3];
    const float* cs        = (const float*)d_in[4];
    const float* cell      = (const float*)d_in[5];
    const int*   img       = (const int*)  d_in[6];
    const float* wlin_in   = (const float*)d_in[7];
    const float* mw1       = (const float*)d_in[8];
    const float* mb1       = (const float*)d_in[9];
    const float* mw2       = (const float*)d_in[10];
    const float* wss       = (const float*)d_in[11];
    const float* wsv       = (const float*)d_in[12];
    const float* wg        = (const float*)d_in[13];
    const float* wl1       = (const float*)d_in[14];
    const float* wl2       = (const float*)d_in[15];
    int N = in_sizes[0];
    int E = in_sizes[2];

    char* w = (char*)d_ws;
    _Float16* emb = (_Float16*)w; w += (size_t)E * 8 * sizeof(_Float16);  // 8.2 MB
    uint2*  y14  = (uint2*)w;  w += (size_t)E * sizeof(uint2);            // 4.1 MB
    int2*   sdp  = (int2*)w;   w += (size_t)E * sizeof(int2);             // 4.1 MB
    uint2*  nf   = (uint2*)w;  w += (size_t)N * 64 * sizeof(uint2);       // 8.2 MB
    float*  agg  = (float*)w;  w += (size_t)N * 64 * 4 * sizeof(float);   // 16.4 MB
    _Float16* w2f  = (_Float16*)w; w += (size_t)3 * 20480 * sizeof(_Float16);
    _Float16* wgtf = (_Float16*)w; w += (size_t)3 * 3 * 4096 * sizeof(_Float16);
    float*  wl12 = (float*)w;  w += 64 * sizeof(float);
    int*    deg  = (int*)w;    w += (size_t)N * sizeof(int);
    int*    curs = (int*)w;    w += (size_t)N * sizeof(int);

    // single hA buffer, written just-in-time before each edge kernel
    // (L3-hot when read). Layers 1/2 write it from node_update's tail
    // blocks; layer 0 uses the standalone pre kernel.
    size_t used   = (size_t)(w - (char*)d_ws);
    size_t hbytes = (size_t)E * 64 * sizeof(_Float16);     // 65.5 MB
    int nh = (ws_size >= used + hbytes) ? 1 : 0;
    _Float16* hbuf = (_Float16*)w;

    size_t NC = (size_t)N * 64;
    float* aggs = agg;
    float* aggx = agg + NC;
    float* aggy = agg + 2*NC;
    float* aggz = agg + 3*NC;

    hipMemsetAsync(deg, 0, (size_t)N * sizeof(int), stream);
    hipMemsetAsync(agg, 0, NC * 4 * sizeof(float), stream);  // L0 only;
                                                             // node_update
                                                             // zeroes in place
    count_deg<<<(E/4 + 255) / 256, 256, 0, stream>>>(dst, deg, E);
    int prep_n = 3*20480 + 3*3*4096;
    scan_prep<<<1 + (prep_n + 1023) / 1024, 1024, 0, stream>>>(
        deg, curs, N, mw2, w2f, wg, wss, wsv, wgtf, wl1, wl2, wl12);
    edge_pre_scatter<<<(E + 255) / 256, 256, 0, stream>>>(
        pos, src, dst, cs, cell, img, curs, emb, y14, sdp, E);

    int eblocks = (E + 63) / 64;   // l0: 4 waves/block; edge: 4 tiles/block
    int nblocks = (N + 63) / 64;   // 4 waves/block, 16 nodes/wave
    int pblocks = 2048;            // grid-strided mlp1_pre (~8 edges/thread)

    // ---- Layer 0: v==0 specialization ----
    if (nh) {
        mlp1_pre<<<pblocks, 256, 0, stream>>>(emb, mw1, mb1, hbuf, E);
        edge_msg_mfma_l0<true><<<eblocks, 256, 0, stream>>>(
            emb, hbuf, y14, sdp, atom_type, wlin_in,
            mw1, mb1, w2f, aggs, aggx, aggy, aggz, E);
    } else {
        edge_msg_mfma_l0<false><<<eblocks, 256, 0, stream>>>(
            emb, nullptr, y14, sdp, atom_type, wlin_in,
            mw1, mb1, w2f, aggs, aggx, aggy, aggz, E);
    }
    // node L0 + (fused) pre for L1
    node_update_mfma<<<nblocks + (nh ? pblocks : 0), 256, 0, stream>>>(
        nf, aggs, aggx, aggy, aggz, wgtf, atom_type, wlin_in, wl12,
        (float*)d_out, 1, 0, N,
        emb, mw1 + 1 * 8 * 64, mb1 + 1 * 64, hbuf, E, nblocks);

    // ---- Layers 1..2 ----
    for (int L = 1; L < 3; L++) {
        if (nh) {
            edge_msg_mfma<true><<<eblocks, 512, 0, stream>>>(
                emb, hbuf, y14, sdp, nf,
                mw1 + L * 8 * 64, mb1 + L * 64, w2f + (size_t)L * 20480,
                aggs, aggx, aggy, aggz, E);
        } else {
            edge_msg_mfma<false><<<eblocks, 512, 0, stream>>>(
                emb, nullptr, y14, sdp, nf,
                mw1 + L * 8 * 64, mb1 + L * 64, w2f + (size_t)L * 20480,
                aggs, aggx, aggy, aggz, E);
        }
        // node L + (fused) pre for L+1 (only when a next layer exists)
        int fuse = (nh && L < 2) ? pblocks : 0;
        node_update_mfma<<<nblocks + fuse, 256, 0, stream>>>(
            nf, aggs, aggx, aggy, aggz,
            wgtf + (size_t)L * 12288, atom_type, wlin_in, wl12,
            (float*)d_out, 0, (L == 2) ? 1 : 0, N,
            emb, mw1 + (L+1 < 3 ? L+1 : 0) * 8 * 64,
            mb1 + (L+1 < 3 ? L+1 : 0) * 64, hbuf, E,
            fuse ? nblocks : (nblocks + fuse + 1));
    }
}

// Round 11
// 458.826 us; speedup vs baseline: 2.0987x; 1.0172x over previous
//
#include <hip/hip_runtime.h>
#include <hip/hip_fp16.h>
#include <math.h>

#define NUM_BASIS 8
#define SQRT3 1.7320508075688772f
#define SQRT2 1.4142135623730951f
#define INV_SQRT_DEG 0.17677669529663687f   // 1/sqrt(32)
#define PI_F 3.14159265358979323846f

typedef _Float16 half8 __attribute__((ext_vector_type(8)));
typedef float float4v __attribute__((ext_vector_type(4)));

__device__ __forceinline__ float sigmoidf_(float x) { return 1.0f / (1.0f + __expf(-x)); }
__device__ __forceinline__ float siluf_(float x) { return x * sigmoidf_(x); }

__device__ __forceinline__ void unp2(unsigned u, float& a, float& b) {
    __half2 h = *reinterpret_cast<__half2*>(&u);
    float2 f = __half22float2(h);
    a = f.x; b = f.y;
}
__device__ __forceinline__ unsigned pk2(float a, float b) {
    __half2 h = __floats2half2_rn(a, b);
    return *reinterpret_cast<unsigned*>(&h);
}

// R29/R30: bijective XCD-chunked swizzle (guide m204). Default dispatch
// round-robins consecutive blocks across the 8 XCDs; this remap gives each
// XCD a CONTIGUOUS chunk of the grid so its private 4MB L2 holds a compact
// window of nf (gathers) and agg (atomics) instead of a strided sample.
// CONTRACT: nwg must equal the exact number of blocks being swizzled
// (bijection domain) — R29 violated this on the last node_update (nwg was
// nblocks+1 for a grid of nblocks -> one node chunk never updated).
__device__ __forceinline__ int xcd_swz(int bid, int nwg) {
    int q = nwg >> 3, r = nwg & 7;
    int x = bid & 7, i = bid >> 3;
    return (x < r ? x * (q + 1) : r * (q + 1) + (x - r) * q) + i;
}

// ---------------------------------------------------------------------------
// CSR build: degree count (4 edges/thread) -> scan (fused with weight prep)
// ---------------------------------------------------------------------------
__global__ __launch_bounds__(256) void count_deg(
    const int* __restrict__ dst, int* __restrict__ deg, int E)
{
    int base = (blockIdx.x * blockDim.x + threadIdx.x) * 4;
    if (base + 3 < E) {
        int4 d4 = *(const int4*)(dst + base);
        atomicAdd(&deg[d4.x], 1);
        atomicAdd(&deg[d4.y], 1);
        atomicAdd(&deg[d4.z], 1);
        atomicAdd(&deg[d4.w], 1);
    } else {
        for (int e = base; e < E; e++) atomicAdd(&deg[dst[e]], 1);
    }
}

// R24: scan (block 0) fused with weight prep (blocks >= 1).
__global__ __launch_bounds__(1024) void scan_prep(
    const int* __restrict__ deg, int* __restrict__ cursor, int N,
    const float* __restrict__ W2, _Float16* __restrict__ w2f,
    const float* __restrict__ Wg, const float* __restrict__ Ws,
    const float* __restrict__ Wv, _Float16* __restrict__ wgtf,
    const float* __restrict__ Wl1, const float* __restrict__ Wl2,
    float* __restrict__ wl12)
{
    if (blockIdx.x != 0) {
        int idx = ((int)blockIdx.x - 1) * 1024 + (int)threadIdx.x;
        if (idx < 64) {
            float a = 0.f;
            #pragma unroll
            for (int j = 0; j < 16; j++) a = fmaf(Wl1[idx*16 + j], Wl2[j], a);
            wl12[idx] = a;
        }
        if (idx < 3 * 20480) {
            int L  = idx / 20480;
            int r  = idx % 20480;
            int cg = r / 5120;
            int r2 = r % 5120;
            int p  = r2 / 1024;
            int r3 = r2 % 1024;
            int kh = r3 / 512;
            int r4 = r3 % 512;
            int lane = r4 / 8;
            int j  = r4 % 8;
            int k = kh*32 + (lane >> 4)*8 + j;
            int n = p*64 + cg*16 + (lane & 15);
            float val = W2[(size_t)L*20480 + k*320 + n];
            if (p == 1)      val *= 0.5773502691896258f;   // 1/sqrt(3)
            else if (p == 4) val *= 0.7071067811865476f;   // 1/sqrt(2)
            w2f[idx] = (_Float16)val;
        } else if (idx < 3*20480 + 3*3*4096) {
            int idx2 = idx - 3*20480;
            int L   = idx2 / 12288;
            int rem = idx2 % 12288;
            int mat = rem / 4096;
            int r2  = rem % 4096;
            int cg  = r2 / 1024;
            int r3  = r2 % 1024;
            int kh  = r3 / 512;
            int r4  = r3 % 512;
            int lane = r4 / 8;
            int j   = r4 % 8;
            int k = kh*32 + (lane >> 4)*8 + j;
            int n = cg*16 + (lane & 15);
            const float* src = (mat == 0) ? Wg : (mat == 1) ? Ws : Wv;
            wgtf[idx2] = (_Float16)src[(size_t)L*4096 + k*64 + n];
        }
        return;
    }

    __shared__ int wsum[16];
    __shared__ int carry_s, tot_s;
    int tid = threadIdx.x;
    int wid = tid >> 6, lane = tid & 63;
    if (tid == 0) carry_s = 0;
    __syncthreads();
    for (int base = 0; base < N; base += 16384) {
        int i0 = base + tid * 16;
        int v[16];
        int sum = 0;
        #pragma unroll
        for (int k = 0; k < 16; k++) {
            int i = i0 + k;
            v[k] = (i < N) ? deg[i] : 0;
            sum += v[k];
        }
        int incl = sum;
        #pragma unroll
        for (int off = 1; off < 64; off <<= 1) {
            int t = __shfl_up(incl, off);
            if (lane >= off) incl += t;
        }
        if (lane == 63) wsum[wid] = incl;
        __syncthreads();
        if (wid == 0 && lane < 16) {
            int wv = wsum[lane];
            int wincl = wv;
            #pragma unroll
            for (int off = 1; off < 16; off <<= 1) {
                int t = __shfl_up(wincl, off);
                if (lane >= off) wincl += t;
            }
            wsum[lane] = wincl - wv;
            if (lane == 15) tot_s = wincl;
        }
        __syncthreads();
        int carry = carry_s;
        int run = carry + wsum[wid] + incl - sum;   // exclusive prefix at i0
        #pragma unroll
        for (int k = 0; k < 16; k++) {
            int i = i0 + k;
            if (i < N) cursor[i] = run;
            run += v[k];
        }
        __syncthreads();
        if (tid == 0) carry_s = carry + tot_s;
        __syncthreads();
    }
}

// Per-edge geometry + radial embedding, scattered directly into CSR slots.
// emb stored f16x8 (16B), y14 stored f16x4 (8B).
__global__ __launch_bounds__(256) void edge_pre_scatter(
    const float* __restrict__ pos, const int* __restrict__ src,
    const int* __restrict__ dst, const float* __restrict__ cs,
    const float* __restrict__ cell, const int* __restrict__ img,
    int* __restrict__ cursor, _Float16* __restrict__ emb,
    uint2* __restrict__ y14, int2* __restrict__ sdp, int E)
{
    int e = blockIdx.x * blockDim.x + threadIdx.x;
    if (e >= E) return;
    int si = src[e], di = dst[e];
    int slot = atomicAdd(&cursor[di], 1);
    sdp[slot] = make_int2(si, di);
    float vx = pos[di*3+0] - pos[si*3+0];
    float vy = pos[di*3+1] - pos[si*3+1];
    float vz = pos[di*3+2] - pos[si*3+2];
    float c0 = cs[(size_t)e*3+0], c1 = cs[(size_t)e*3+1], c2 = cs[(size_t)e*3+2];
    const float* M = cell + (size_t)img[si] * 9;
    vx += c0*M[0] + c1*M[3] + c2*M[6];
    vy += c0*M[1] + c1*M[4] + c2*M[7];
    vz += c0*M[2] + c1*M[5] + c2*M[8];
    float r  = sqrtf(vx*vx + vy*vy + vz*vz);
    float rs = fmaxf(r, 1e-9f);
    float inv = 1.0f / rs;
    uint2 yv;
    yv.x = pk2(SQRT3*vx*inv, SQRT3*vy*inv);
    yv.y = pk2(SQRT3*vz*inv, 0.f);
    y14[slot] = yv;
    // polynomial cutoff p=6: 1 - 28 x^6 + 48 x^7 - 21 x^8 (0 for x>=1)
    float x = r * (1.0f / 5.0f);
    float x2 = x*x, x6 = x2*x2*x2;
    float fc = 1.0f - 28.0f*x6 + 48.0f*x6*x - 21.0f*x6*x2;
    if (x >= 1.0f) fc = 0.0f;
    float pre = sqrtf(2.0f / 5.0f) * inv * fc;
    float t = PI_F * rs * (1.0f / 5.0f);
    half8 ev;
    #pragma unroll
    for (int n = 1; n <= NUM_BASIS; n++)
        ev[n-1] = (_Float16)(pre * __sinf((float)n * t));
    *(half8*)(emb + (size_t)slot*NUM_BASIS) = ev;
}

// ---------------------------------------------------------------------------
// MLP1 precompute body (R23 grid-strided, weights in registers). Standalone
// kernel for L0; the same body runs in tail blocks of node_update (R24).
// ---------------------------------------------------------------------------
__device__ __forceinline__ void mlp1_pre_body(
    const _Float16* __restrict__ emb, const float* __restrict__ W1,
    const float* __restrict__ B1, _Float16* __restrict__ hA, int E,
    int g, int nthreads)
{
    int kb   = (g & 7) * 8;
    int es   = g >> 3;
    int estr = nthreads >> 3;
    float wv[8][8];
    #pragma unroll
    for (int jj = 0; jj < 8; jj++) {
        float4 a = *(const float4*)(W1 + jj*64 + kb);
        float4 b = *(const float4*)(W1 + jj*64 + kb + 4);
        wv[jj][0]=a.x; wv[jj][1]=a.y; wv[jj][2]=a.z; wv[jj][3]=a.w;
        wv[jj][4]=b.x; wv[jj][5]=b.y; wv[jj][6]=b.z; wv[jj][7]=b.w;
    }
    float bv[8];
    {
        float4 a = *(const float4*)(B1 + kb);
        float4 b = *(const float4*)(B1 + kb + 4);
        bv[0]=a.x; bv[1]=a.y; bv[2]=a.z; bv[3]=a.w;
        bv[4]=b.x; bv[5]=b.y; bv[6]=b.z; bv[7]=b.w;
    }
    for (int e = es; e < E; e += estr) {
        half8 ev = *(const half8*)(emb + (size_t)e*8);
        float hv[8];
        #pragma unroll
        for (int j = 0; j < 8; j++) hv[j] = bv[j];
        #pragma unroll
        for (int jj = 0; jj < 8; jj++) {
            float em = (float)ev[jj];
            #pragma unroll
            for (int j = 0; j < 8; j++)
                hv[j] = fmaf(em, wv[jj][j], hv[j]);
        }
        half8 out;
        #pragma unroll
        for (int j = 0; j < 8; j++) out[j] = (_Float16)siluf_(hv[j]);
        *(half8*)(hA + (size_t)e*64 + kb) = out;
    }
}

__global__ __launch_bounds__(256) void mlp1_pre(
    const _Float16* __restrict__ emb, const float* __restrict__ W1,
    const float* __restrict__ B1, _Float16* __restrict__ hA, int E)
{
    int g = blockIdx.x * blockDim.x + threadIdx.x;
    mlp1_pre_body(emb, W1, B1, hA, E, g, gridDim.x * blockDim.x);
}

// ---------------------------------------------------------------------------
// A-frag MLP1 (fallback when workspace can't hold hA)
// ---------------------------------------------------------------------------
__device__ __forceinline__ void mlp1_afrag(
    const _Float16* __restrict__ emb, const float* __restrict__ W1,
    const float* __restrict__ B1, int eA, int q, half8 afrag[2])
{
    half8 ev = *(const half8*)(emb + (size_t)eA*8);
    float em[8];
    #pragma unroll
    for (int j = 0; j < 8; j++) em[j] = (float)ev[j];
    #pragma unroll
    for (int kh = 0; kh < 2; kh++) {
        int kb = kh*32 + q*8;
        float hv[8];
        float4 b0 = *(const float4*)(B1 + kb);
        float4 b1 = *(const float4*)(B1 + kb + 4);
        hv[0]=b0.x; hv[1]=b0.y; hv[2]=b0.z; hv[3]=b0.w;
        hv[4]=b1.x; hv[5]=b1.y; hv[6]=b1.z; hv[7]=b1.w;
        #pragma unroll
        for (int jj = 0; jj < 8; jj++) {
            float4 wa = *(const float4*)(W1 + jj*64 + kb);
            float4 wb = *(const float4*)(W1 + jj*64 + kb + 4);
            hv[0] = fmaf(em[jj], wa.x, hv[0]);
            hv[1] = fmaf(em[jj], wa.y, hv[1]);
            hv[2] = fmaf(em[jj], wa.z, hv[2]);
            hv[3] = fmaf(em[jj], wa.w, hv[3]);
            hv[4] = fmaf(em[jj], wb.x, hv[4]);
            hv[5] = fmaf(em[jj], wb.y, hv[5]);
            hv[6] = fmaf(em[jj], wb.z, hv[6]);
            hv[7] = fmaf(em[jj], wb.w, hv[7]);
        }
        #pragma unroll
        for (int j = 0; j < 8; j++)
            afrag[kh][j] = (_Float16)siluf_(hv[j]);
    }
}

// R30: R29 with the swizzle-domain bug fixed (nb_node == real main-block
// count everywhere). Structure = R24/R25 anchor (450us) + XCD swizzle.
// ---------------------------------------------------------------------------
// Layer-0 edge kernel: v == 0 -> only w1/w3 paths, 16 KB LDS.
// ---------------------------------------------------------------------------
template<bool PRE>
__global__ __launch_bounds__(256) void edge_msg_mfma_l0(
    const _Float16* __restrict__ emb, const _Float16* __restrict__ hA,
    const uint2* __restrict__ y14, const int2* __restrict__ sdp,
    const int* __restrict__ type, const float* __restrict__ wlin,
    const float* __restrict__ W1, const float* __restrict__ B1,
    const _Float16* __restrict__ w2f,
    float* __restrict__ aggs, float* __restrict__ aggx,
    float* __restrict__ aggy, float* __restrict__ aggz, int E)
{
    __shared__ _Float16 w2s[8192];   // 16 KB: [cg][pp in {p0,p2}][kh][512]
    {
        half8* dstv = (half8*)w2s;
        const half8* srcv = (const half8*)w2f;
        #pragma unroll
        for (int k = 0; k < 4; k++) {
            int t  = threadIdx.x + k*256;
            int cg = t >> 8;
            int r  = t & 255;
            int pp = r >> 7;          // 0 -> path 0 (w1), 1 -> path 2 (w3)
            int rk = r & 127;         // kh*64 + lane
            dstv[t] = srcv[cg*640 + pp*256 + rk];
        }
    }
    __syncthreads();

    int wave  = xcd_swz(blockIdx.x, gridDim.x) * 4 + ((int)threadIdx.x >> 6);
    int lane  = threadIdx.x & 63;
    int wbase = wave * 16;
    if (wbase >= E) return;
    int q   = lane >> 4;
    int col = lane & 15;

    half8 afrag[2];
    if (PRE) {
        const _Float16* hp = hA + (size_t)(wbase + col)*64 + q*8;
        afrag[0] = *(const half8*)(hp);
        afrag[1] = *(const half8*)(hp + 32);
    }

    int eb = wbase + q*4;
    int d[4], tt[4];
    float y1x[4], y1y[4], y1z[4];
    #pragma unroll
    for (int r = 0; r < 4; r++) {
        int2 sv = sdp[eb + r];
        tt[r] = type[sv.x];
        d[r]  = sv.y;
        uint2 yv = y14[eb + r];
        float dummy;
        unp2(yv.x, y1x[r], y1y[r]);
        unp2(yv.y, y1z[r], dummy);
    }

    if (!PRE) mlp1_afrag(emb, W1, B1, wbase + col, q, afrag);

    int dfirst = __shfl(d[0], 0);
    bool uni = __all(d[3] == dfirst);     // dst-sorted -> all 16 equal

    int dnq = __shfl_down(d[0], 16);      // next quad's first dst
    int nd3 = (q == 3) ? -1 : dnq;        // q3 reg3: forced tail
    int df = d[0], dl = d[3];
    bool U = (df == dl);
    int dlp = __shfl_up(dl, 16);
    bool link = (q > 0) && (dlp == df);

    #pragma unroll
    for (int cg = 0; cg < 4; cg++) {
        float4v a1 = {0,0,0,0}, a3 = {0,0,0,0};
        const _Float16* wbp = w2s + ((size_t)cg*2048) + (size_t)lane*8;
        {
            half8 b10 = *(const half8*)(wbp + 0*512);
            half8 b11 = *(const half8*)(wbp + 1*512);
            half8 b30 = *(const half8*)(wbp + 2*512);
            half8 b31 = *(const half8*)(wbp + 3*512);
            a1 = __builtin_amdgcn_mfma_f32_16x16x32_f16(afrag[0], b10, a1, 0, 0, 0);
            a1 = __builtin_amdgcn_mfma_f32_16x16x32_f16(afrag[1], b11, a1, 0, 0, 0);
            a3 = __builtin_amdgcn_mfma_f32_16x16x32_f16(afrag[0], b30, a3, 0, 0, 0);
            a3 = __builtin_amdgcn_mfma_f32_16x16x32_f16(afrag[1], b31, a3, 0, 0, 0);
        }
        int c = cg*16 + col;

        float ms[4], mx[4], my[4], mz[4];
        #pragma unroll
        for (int r = 0; r < 4; r++) {
            float s = wlin[tt[r]*64 + c];
            float w3s = a3[r] * s;
            ms[r] = a1[r] * s;
            mx[r] = w3s * y1x[r];
            my[r] = w3s * y1y[r];
            mz[r] = w3s * y1z[r];
        }

        if (uni) {
            float fs = (ms[0]+ms[1]) + (ms[2]+ms[3]);
            float fx = (mx[0]+mx[1]) + (mx[2]+mx[3]);
            float fy = (my[0]+my[1]) + (my[2]+my[3]);
            float fz = (mz[0]+mz[1]) + (mz[2]+mz[3]);
            fs += __shfl_xor(fs, 16); fx += __shfl_xor(fx, 16);
            fy += __shfl_xor(fy, 16); fz += __shfl_xor(fz, 16);
            fs += __shfl_xor(fs, 32); fx += __shfl_xor(fx, 32);
            fy += __shfl_xor(fy, 32); fz += __shfl_xor(fz, 32);
            if (q == 0) {
                size_t ai = (size_t)d[0]*64 + c;
                atomicAdd(aggs + ai, fs);
                atomicAdd(aggx + ai, fx);
                atomicAdd(aggy + ai, fy);
                atomicAdd(aggz + ai, fz);
            }
            continue;
        }

        #pragma unroll
        for (int r = 1; r < 4; r++) {
            if (d[r] == d[r-1]) {
                ms[r] += ms[r-1]; mx[r] += mx[r-1];
                my[r] += my[r-1]; mz[r] += mz[r-1];
            }
        }
        // cross-quad carry (chains up to 4 quads -> 3 iterations)
        float Cs = 0.f, Cx = 0.f, Cy = 0.f, Cz = 0.f;
        #pragma unroll
        for (int it = 0; it < 3; it++) {
            float es = ms[3] + (U ? Cs : 0.f);
            float ex = mx[3] + (U ? Cx : 0.f);
            float ey = my[3] + (U ? Cy : 0.f);
            float ez = mz[3] + (U ? Cz : 0.f);
            float ts = __shfl_up(es, 16);
            float tx = __shfl_up(ex, 16);
            float ty = __shfl_up(ey, 16);
            float tz = __shfl_up(ez, 16);
            Cs = link ? ts : 0.f; Cx = link ? tx : 0.f;
            Cy = link ? ty : 0.f; Cz = link ? tz : 0.f;
        }
        bool hr = true;
        #pragma unroll
        for (int r = 0; r < 4; r++) {
            if (r > 0) hr = hr && (d[r] == d[r-1]);
            float fs = ms[r] + (hr ? Cs : 0.f);
            float fx = mx[r] + (hr ? Cx : 0.f);
            float fy = my[r] + (hr ? Cy : 0.f);
            float fz = mz[r] + (hr ? Cz : 0.f);
            int ndx = (r < 3) ? d[r+1] : nd3;
            if (ndx != d[r] && d[r] >= 0) {
                size_t ai = (size_t)d[r]*64 + c;
                atomicAdd(aggs + ai, fs);
                atomicAdd(aggx + ai, fx);
                atomicAdd(aggy + ai, fy);
                atomicAdd(aggz + ai, fz);
            }
        }
    }
}

// ---------------------------------------------------------------------------
// Process two cg's (one staged LDS half) of the general edge kernel.
// ---------------------------------------------------------------------------
__device__ __forceinline__ void process_half(
    const _Float16* __restrict__ w2s, const half8 afrag[2],
    const uint2 pf[4][2], const int d[4], int nd3, bool U, bool link,
    bool uni, const float* y1x, const float* y1y, const float* y1z,
    int cgh, int col,
    float* __restrict__ aggs, float* __restrict__ aggx,
    float* __restrict__ aggy, float* __restrict__ aggz)
{
    int lane = threadIdx.x & 63;
    int q = lane >> 4;
    #pragma unroll
    for (int cgl = 0; cgl < 2; cgl++) {
        float4v acc[5];
        #pragma unroll
        for (int p = 0; p < 5; p++) acc[p] = (float4v){0.f, 0.f, 0.f, 0.f};
        const _Float16* wbp = w2s + ((size_t)cgl*5120) + (size_t)lane*8;
        #pragma unroll
        for (int p = 0; p < 5; p++) {
            half8 bf0 = *(const half8*)(wbp + ((size_t)(p*2 + 0))*512);
            half8 bf1 = *(const half8*)(wbp + ((size_t)(p*2 + 1))*512);
            acc[p] = __builtin_amdgcn_mfma_f32_16x16x32_f16(afrag[0], bf0, acc[p], 0, 0, 0);
            acc[p] = __builtin_amdgcn_mfma_f32_16x16x32_f16(afrag[1], bf1, acc[p], 0, 0, 0);
        }
        int c = (cgh*2 + cgl)*16 + col;

        float ms[4], mx[4], my[4], mz[4];
        #pragma unroll
        for (int r = 0; r < 4; r++) {
            float fsx, fvx, fvy, fvz;
            unp2(pf[r][cgl].x, fsx, fvx);
            unp2(pf[r][cgl].y, fvy, fvz);
            float yx = y1x[r], yy = y1y[r], yz = y1z[r];
            float w1 = acc[0][r], w2 = acc[1][r], w3 = acc[2][r];
            float w4 = acc[3][r], w5 = acc[4][r];
            float vdoty = fvx*yx + fvy*yy + fvz*yz;
            ms[r] = fmaf(w1, fsx, w2*vdoty);           // w2 pre-scaled 1/sqrt3
            float w3s = w3*fsx;
            float cx = fvy*yz - fvz*yy;
            float cy = fvz*yx - fvx*yz;
            float cz = fvx*yy - fvy*yx;
            mx[r] = fmaf(w3s, yx, fmaf(w4, fvx, w5*cx));  // w5 pre-scaled 1/sqrt2
            my[r] = fmaf(w3s, yy, fmaf(w4, fvy, w5*cy));
            mz[r] = fmaf(w3s, yz, fmaf(w4, fvz, w5*cz));
        }

        if (uni) {
            float fs = (ms[0]+ms[1]) + (ms[2]+ms[3]);
            float fx = (mx[0]+mx[1]) + (mx[2]+mx[3]);
            float fy = (my[0]+my[1]) + (my[2]+my[3]);
            float fz = (mz[0]+mz[1]) + (mz[2]+mz[3]);
            fs += __shfl_xor(fs, 16); fx += __shfl_xor(fx, 16);
            fy += __shfl_xor(fy, 16); fz += __shfl_xor(fz, 16);
            fs += __shfl_xor(fs, 32); fx += __shfl_xor(fx, 32);
            fy += __shfl_xor(fy, 32); fz += __shfl_xor(fz, 32);
            if (q == 0) {
                size_t ai = (size_t)d[0]*64 + c;
                atomicAdd(aggs + ai, fs);
                atomicAdd(aggx + ai, fx);
                atomicAdd(aggy + ai, fy);
                atomicAdd(aggz + ai, fz);
            }
            continue;
        }

        #pragma unroll
        for (int r = 1; r < 4; r++) {
            if (d[r] == d[r-1]) {
                ms[r] += ms[r-1]; mx[r] += mx[r-1];
                my[r] += my[r-1]; mz[r] += mz[r-1];
            }
        }
        float Cs = 0.f, Cx = 0.f, Cy = 0.f, Cz = 0.f;
        #pragma unroll
        for (int it = 0; it < 3; it++) {
            float es = ms[3] + (U ? Cs : 0.f);
            float ex = mx[3] + (U ? Cx : 0.f);
            float ey = my[3] + (U ? Cy : 0.f);
            float ez = mz[3] + (U ? Cz : 0.f);
            float ts = __shfl_up(es, 16);
            float tx = __shfl_up(ex, 16);
            float ty = __shfl_up(ey, 16);
            float tz = __shfl_up(ez, 16);
            Cs = link ? ts : 0.f; Cx = link ? tx : 0.f;
            Cy = link ? ty : 0.f; Cz = link ? tz : 0.f;
        }
        bool hr = true;
        #pragma unroll
        for (int r = 0; r < 4; r++) {
            if (r > 0) hr = hr && (d[r] == d[r-1]);
            float fs = ms[r] + (hr ? Cs : 0.f);
            float fx = mx[r] + (hr ? Cx : 0.f);
            float fy = my[r] + (hr ? Cy : 0.f);
            float fz = mz[r] + (hr ? Cz : 0.f);
            int ndx = (r < 3) ? d[r+1] : nd3;
            if (ndx != d[r] && d[r] >= 0) {
                size_t ai = (size_t)d[r]*64 + c;
                atomicAdd(aggs + ai, fs);
                atomicAdd(aggx + ai, fx);
                atomicAdd(aggy + ai, fy);
                atomicAdd(aggz + ai, fz);
            }
        }
    }
}

// ---------------------------------------------------------------------------
// General MFMA edge kernel (layers >= 1): one wave per 16 CSR edges, ALL 4
// cg per wave. 20 KB LDS time-multiplexed (R21): stage cg{0,1}, compute,
// re-stage cg{2,3}. pf regs reloaded for cols 32-63 after last use. Raw
// barriers (lgkmcnt-only) keep atomics + pf2 loads in flight.
// PRE: afrag from hA. R24 uni fast path. R29/R30 XCD swizzle.
// ---------------------------------------------------------------------------
template<bool PRE>
__global__ __launch_bounds__(256) void edge_msg_mfma(
    const _Float16* __restrict__ emb, const _Float16* __restrict__ hA,
    const uint2* __restrict__ y14, const int2* __restrict__ sdp,
    const uint2* __restrict__ nf,
    const float* __restrict__ W1, const float* __restrict__ B1,
    const _Float16* __restrict__ w2f,
    float* __restrict__ aggs, float* __restrict__ aggx,
    float* __restrict__ aggy, float* __restrict__ aggz, int E)
{
    __shared__ _Float16 w2s[10240];   // 20 KB: two cg's worth of B-frags
    {
        half8* dstv = (half8*)w2s;
        const half8* srcv = (const half8*)w2f;           // half 0: cgs {0,1}
        #pragma unroll
        for (int k = 0; k < 5; k++)
            dstv[threadIdx.x + k*256] = srcv[threadIdx.x + k*256];
    }
    __syncthreads();

    int wave  = xcd_swz(blockIdx.x, gridDim.x) * 4 + ((int)threadIdx.x >> 6);
    int lane  = threadIdx.x & 63;
    int wbase = wave * 16;
    bool live = wbase < E;
    int wb2   = live ? wbase : 0;     // clamp; dead waves skip atomics only
    int q   = lane >> 4;
    int col = lane & 15;

    half8 afrag[2];
    if (PRE) {
        const _Float16* hp = hA + (size_t)(wb2 + col)*64 + q*8;
        afrag[0] = *(const half8*)(hp);
        afrag[1] = *(const half8*)(hp + 32);
    }

    int eb = wb2 + q*4;
    int d[4], si[4];
    float y1x[4], y1y[4], y1z[4];
    #pragma unroll
    for (int r = 0; r < 4; r++) {
        int2 sv = sdp[eb + r];
        si[r] = sv.x;
        d[r]  = sv.y;
        uint2 yv = y14[eb + r];
        float dummy;
        unp2(yv.x, y1x[r], y1y[r]);
        unp2(yv.y, y1z[r], dummy);
    }

    // nf prefetch for cols 0-31 (R11)
    uint2 pf[4][2];
    #pragma unroll
    for (int r = 0; r < 4; r++) {
        size_t nb = (size_t)si[r] * 64 + col;
        pf[r][0] = nf[nb];
        pf[r][1] = nf[nb + 16];
    }

    if (!PRE) mlp1_afrag(emb, W1, B1, wb2 + col, q, afrag);

    int dfirst = __shfl(d[0], 0);
    bool uni = __all(d[3] == dfirst) && live;

    int dnq = __shfl_down(d[0], 16);
    int nd3 = (q == 3) ? -1 : dnq;
    int df = d[0], dl = d[3];
    bool U = (df == dl);
    int dlp = __shfl_up(dl, 16);
    bool link = (q > 0) && (dlp == df);
    if (!live) { d[0] = -1; d[1] = -1; d[2] = -1; d[3] = -1; }

    // ---- cg 0,1 from LDS half 0 ----
    process_half(w2s, afrag, pf, d, nd3, U, link, uni,
                 y1x, y1y, y1z, 0, col, aggs, aggx, aggy, aggz);

    // reload pf with cols 32-63 (issued before the barrier; latency hides
    // under barrier + re-stage + cg2 MFMAs)
    #pragma unroll
    for (int r = 0; r < 4; r++) {
        size_t nb = (size_t)si[r] * 64 + 32 + col;
        pf[r][0] = nf[nb];
        pf[r][1] = nf[nb + 16];
    }

    // all waves done READING half 0 (lgkm only; atomics stay in flight)
    asm volatile("s_waitcnt lgkmcnt(0)" ::: "memory");
    __builtin_amdgcn_s_barrier();
    asm volatile("" ::: "memory");

    {   // re-stage: cgs {2,3}
        half8* dstv = (half8*)w2s;
        const half8* srcv = (const half8*)w2f + 1280;
        #pragma unroll
        for (int k = 0; k < 5; k++)
            dstv[threadIdx.x + k*256] = srcv[threadIdx.x + k*256];
    }

    // all waves done WRITING half 1
    asm volatile("s_waitcnt lgkmcnt(0)" ::: "memory");
    __builtin_amdgcn_s_barrier();
    asm volatile("" ::: "memory");

    // ---- cg 2,3 from LDS half 1 ----
    process_half(w2s, afrag, pf, d, nd3, U, link, uni,
                 y1x, y1y, y1z, 1, col, aggs, aggx, aggy, aggz);
}

// ---------------------------------------------------------------------------
// MFMA node update: one wave per 16 nodes (R12). wgtf staged in LDS.
// first=1 (L0): residual s from wlin[type], v = 0. Epilogue zeroes agg in
// place; fused energy projection on last layer.
// R24: tail blocks (blockIdx >= nb_node) run mlp1_pre for the NEXT layer.
// R30: XCD swizzle on main blocks; nb_node MUST equal the real main-block
// count (swizzle bijection domain).
// ---------------------------------------------------------------------------
__global__ __launch_bounds__(256) void node_update_mfma(
    uint2* __restrict__ nf,
    float* __restrict__ aggs, float* __restrict__ aggx,
    float* __restrict__ aggy, float* __restrict__ aggz,
    const _Float16* __restrict__ wgtf,
    const int* __restrict__ type, const float* __restrict__ wlin,
    const float* __restrict__ wl12,
    float* __restrict__ out, int first, int do_out, int N,
    const _Float16* __restrict__ emb, const float* __restrict__ W1n,
    const float* __restrict__ B1n, _Float16* __restrict__ hA, int E,
    int nb_node)
{
    if ((int)blockIdx.x >= nb_node) {
        int g = ((int)blockIdx.x - nb_node) * 256 + (int)threadIdx.x;
        mlp1_pre_body(emb, W1n, B1n, hA, E, g,
                      ((int)gridDim.x - nb_node) * 256);
        return;
    }

    __shared__ _Float16 wgs[12288];   // 24.6 KB
    {
        half8* dstv = (half8*)wgs;
        const half8* srcv = (const half8*)wgtf;
        #pragma unroll
        for (int k = 0; k < 6; k++)
            dstv[threadIdx.x + k*256] = srcv[threadIdx.x + k*256];
    }

    int wave  = xcd_swz(blockIdx.x, nb_node) * 4 + ((int)threadIdx.x >> 6);
    int lane  = threadIdx.x & 63;
    int wbase = wave * 16;
    bool active = wbase < N;
    int q = lane >> 4, col = lane & 15;

    int nodeA = active ? (wbase + col) : 0;
    if (nodeA >= N) nodeA = N - 1;
    size_t nb = (size_t)nodeA * 64 + q * 8;
    half8 af0[2], af1[2], af2[2], af3[2];
    #pragma unroll
    for (int kh = 0; kh < 2; kh++) {
        const float* p0 = aggs + nb + kh*32;
        const float* p1 = aggx + nb + kh*32;
        const float* p2 = aggy + nb + kh*32;
        const float* p3 = aggz + nb + kh*32;
        float4 a0 = *(const float4*)p0, b0 = *(const float4*)(p0+4);
        float4 a1 = *(const float4*)p1, b1 = *(const float4*)(p1+4);
        float4 a2 = *(const float4*)p2, b2 = *(const float4*)(p2+4);
        float4 a3 = *(const float4*)p3, b3 = *(const float4*)(p3+4);
        af0[kh][0]=(_Float16)(a0.x*INV_SQRT_DEG); af0[kh][1]=(_Float16)(a0.y*INV_SQRT_DEG);
        af0[kh][2]=(_Float16)(a0.z*INV_SQRT_DEG); af0[kh][3]=(_Float16)(a0.w*INV_SQRT_DEG);
        af0[kh][4]=(_Float16)(b0.x*INV_SQRT_DEG); af0[kh][5]=(_Float16)(b0.y*INV_SQRT_DEG);
        af0[kh][6]=(_Float16)(b0.z*INV_SQRT_DEG); af0[kh][7]=(_Float16)(b0.w*INV_SQRT_DEG);
        af1[kh][0]=(_Float16)(a1.x*INV_SQRT_DEG); af1[kh][1]=(_Float16)(a1.y*INV_SQRT_DEG);
        af1[kh][2]=(_Float16)(a1.z*INV_SQRT_DEG); af1[kh][3]=(_Float16)(a1.w*INV_SQRT_DEG);
        af1[kh][4]=(_Float16)(b1.x*INV_SQRT_DEG); af1[kh][5]=(_Float16)(b1.y*INV_SQRT_DEG);
        af1[kh][6]=(_Float16)(b1.z*INV_SQRT_DEG); af1[kh][7]=(_Float16)(b1.w*INV_SQRT_DEG);
        af2[kh][0]=(_Float16)(a2.x*INV_SQRT_DEG); af2[kh][1]=(_Float16)(a2.y*INV_SQRT_DEG);
        af2[kh][2]=(_Float16)(a2.z*INV_SQRT_DEG); af2[kh][3]=(_Float16)(a2.w*INV_SQRT_DEG);
        af2[kh][4]=(_Float16)(b2.x*INV_SQRT_DEG); af2[kh][5]=(_Float16)(b2.y*INV_SQRT_DEG);
        af2[kh][6]=(_Float16)(b2.z*INV_SQRT_DEG); af2[kh][7]=(_Float16)(b2.w*INV_SQRT_DEG);
        af3[kh][0]=(_Float16)(a3.x*INV_SQRT_DEG); af3[kh][1]=(_Float16)(a3.y*INV_SQRT_DEG);
        af3[kh][2]=(_Float16)(a3.z*INV_SQRT_DEG); af3[kh][3]=(_Float16)(a3.w*INV_SQRT_DEG);
        af3[kh][4]=(_Float16)(b3.x*INV_SQRT_DEG); af3[kh][5]=(_Float16)(b3.y*INV_SQRT_DEG);
        af3[kh][6]=(_Float16)(b3.z*INV_SQRT_DEG); af3[kh][7]=(_Float16)(b3.w*INV_SQRT_DEG);
    }

    int tt[4];
    #pragma unroll
    for (int r = 0; r < 4; r++) {
        int nd = wbase + q*4 + r;
        tt[r] = type[(active && nd < N) ? nd : 0];
    }

    __syncthreads();   // wgs staged; all waves arrive

    float epart[4] = {0.f, 0.f, 0.f, 0.f};

    #pragma unroll
    for (int cg = 0; cg < 4; cg++) {
        const _Float16* bp = wgs + (size_t)lane * 8;
        half8 bg0 = *(const half8*)(bp + ((size_t)((0*4 + cg)*2 + 0))*512);
        half8 bg1 = *(const half8*)(bp + ((size_t)((0*4 + cg)*2 + 1))*512);
        half8 bs0 = *(const half8*)(bp + ((size_t)((1*4 + cg)*2 + 0))*512);
        half8 bs1 = *(const half8*)(bp + ((size_t)((1*4 + cg)*2 + 1))*512);
        half8 bv0 = *(const half8*)(bp + ((size_t)((2*4 + cg)*2 + 0))*512);
        half8 bv1 = *(const half8*)(bp + ((size_t)((2*4 + cg)*2 + 1))*512);
        float4v ag = {0,0,0,0}, as = {0,0,0,0};
        float4v ox = {0,0,0,0}, oy = {0,0,0,0}, oz = {0,0,0,0};
        ag = __builtin_amdgcn_mfma_f32_16x16x32_f16(af0[0], bg0, ag, 0, 0, 0);
        ag = __builtin_amdgcn_mfma_f32_16x16x32_f16(af0[1], bg1, ag, 0, 0, 0);
        as = __builtin_amdgcn_mfma_f32_16x16x32_f16(af0[0], bs0, as, 0, 0, 0);
        as = __builtin_amdgcn_mfma_f32_16x16x32_f16(af0[1], bs1, as, 0, 0, 0);
        ox = __builtin_amdgcn_mfma_f32_16x16x32_f16(af1[0], bv0, ox, 0, 0, 0);
        ox = __builtin_amdgcn_mfma_f32_16x16x32_f16(af1[1], bv1, ox, 0, 0, 0);
        oy = __builtin_amdgcn_mfma_f32_16x16x32_f16(af2[0], bv0, oy, 0, 0, 0);
        oy = __builtin_amdgcn_mfma_f32_16x16x32_f16(af2[1], bv1, oy, 0, 0, 0);
        oz = __builtin_amdgcn_mfma_f32_16x16x32_f16(af3[0], bv0, oz, 0, 0, 0);
        oz = __builtin_amdgcn_mfma_f32_16x16x32_f16(af3[1], bv1, oz, 0, 0, 0);

        if (!active) continue;
        int c = cg*16 + col;
        float wlc = wl12[c];
        #pragma unroll
        for (int r = 0; r < 4; r++) {
            int nd = wbase + q*4 + r;
            bool wr = nd < N;
            size_t ni = (size_t)nd*64 + c;
            float sx, vx, vy, vz;
            if (first) {
                sx = wlin[tt[r]*64 + c];
                vx = 0.f; vy = 0.f; vz = 0.f;
            } else {
                uint2 cur = nf[wr ? ni : 0];
                unp2(cur.x, sx, vx);
                unp2(cur.y, vy, vz);
            }
            float gate = sigmoidf_(ag[r]);
            sx += siluf_(as[r]);
            vx += ox[r] * gate;
            vy += oy[r] * gate;
            vz += oz[r] * gate;
            if (wr) {
                uint2 nv;
                nv.x = pk2(sx, vx);
                nv.y = pk2(vy, vz);
                nf[ni] = nv;
                aggs[ni] = 0.f;   // in-place zero replaces per-layer memset
                aggx[ni] = 0.f;
                aggy[ni] = 0.f;
                aggz[ni] = 0.f;
                epart[r] = fmaf(sx, wlc, epart[r]);
            }
        }
    }
    if (do_out && active) {
        #pragma unroll
        for (int r = 0; r < 4; r++) {
            float e = epart[r];
            e += __shfl_xor(e, 1);
            e += __shfl_xor(e, 2);
            e += __shfl_xor(e, 4);
            e += __shfl_xor(e, 8);
            int nd = wbase + q*4 + r;
            if (col == 0 && nd < N) out[nd] = e;
        }
    }
}

extern "C" void kernel_launch(void* const* d_in, const int* in_sizes, int n_in,
                              void* d_out, int out_size, void* d_ws, size_t ws_size,
                              hipStream_t stream)
{
    const int*   atom_type = (const int*)  d_in[0];
    const float* pos       = (const float*)d_in[1];
    const int*   src       = (const int*)  d_in[2];
    const int*   dst       = (const int*)  d_in[3];
    const float* cs        = (const float*)d_in[4];
    const float* cell      = (const float*)d_in[5];
    const int*   img       = (const int*)  d_in[6];
    const float* wlin_in   = (const float*)d_in[7];
    const float* mw1       = (const float*)d_in[8];
    const float* mb1       = (const float*)d_in[9];
    const float* mw2       = (const float*)d_in[10];
    const float* wss       = (const float*)d_in[11];
    const float* wsv       = (const float*)d_in[12];
    const float* wg        = (const float*)d_in[13];
    const float* wl1       = (const float*)d_in[14];
    const float* wl2       = (const float*)d_in[15];
    int N = in_sizes[0];
    int E = in_sizes[2];

    char* w = (char*)d_ws;
    _Float16* emb = (_Float16*)w; w += (size_t)E * 8 * sizeof(_Float16);  // 8.2 MB
    uint2*  y14  = (uint2*)w;  w += (size_t)E * sizeof(uint2);            // 4.1 MB
    int2*   sdp  = (int2*)w;   w += (size_t)E * sizeof(int2);             // 4.1 MB
    uint2*  nf   = (uint2*)w;  w += (size_t)N * 64 * sizeof(uint2);       // 8.2 MB
    float*  agg  = (float*)w;  w += (size_t)N * 64 * 4 * sizeof(float);   // 16.4 MB
    _Float16* w2f  = (_Float16*)w; w += (size_t)3 * 20480 * sizeof(_Float16);
    _Float16* wgtf = (_Float16*)w; w += (size_t)3 * 3 * 4096 * sizeof(_Float16);
    float*  wl12 = (float*)w;  w += 64 * sizeof(float);
    int*    deg  = (int*)w;    w += (size_t)N * sizeof(int);
    int*    curs = (int*)w;    w += (size_t)N * sizeof(int);

    // single hA buffer, written just-in-time before each edge kernel
    // (L3-hot when read). Layers 1/2 write it from node_update's tail
    // blocks; layer 0 uses the standalone pre kernel.
    size_t used   = (size_t)(w - (char*)d_ws);
    size_t hbytes = (size_t)E * 64 * sizeof(_Float16);     // 65.5 MB
    int nh = (ws_size >= used + hbytes) ? 1 : 0;
    _Float16* hbuf = (_Float16*)w;

    size_t NC = (size_t)N * 64;
    float* aggs = agg;
    float* aggx = agg + NC;
    float* aggy = agg + 2*NC;
    float* aggz = agg + 3*NC;

    hipMemsetAsync(deg, 0, (size_t)N * sizeof(int), stream);
    hipMemsetAsync(agg, 0, NC * 4 * sizeof(float), stream);  // L0 only;
                                                             // node_update
                                                             // zeroes in place
    count_deg<<<(E/4 + 255) / 256, 256, 0, stream>>>(dst, deg, E);
    int prep_n = 3*20480 + 3*3*4096;
    scan_prep<<<1 + (prep_n + 1023) / 1024, 1024, 0, stream>>>(
        deg, curs, N, mw2, w2f, wg, wss, wsv, wgtf, wl1, wl2, wl12);
    edge_pre_scatter<<<(E + 255) / 256, 256, 0, stream>>>(
        pos, src, dst, cs, cell, img, curs, emb, y14, sdp, E);

    int eblocks = (E + 63) / 64;   // 4 waves/block, 16 edges/wave
    int nblocks = (N + 63) / 64;   // 4 waves/block, 16 nodes/wave
    int pblocks = 2048;            // grid-strided mlp1_pre (~8 edges/thread)

    // ---- Layer 0: v==0 specialization ----
    if (nh) {
        mlp1_pre<<<pblocks, 256, 0, stream>>>(emb, mw1, mb1, hbuf, E);
        edge_msg_mfma_l0<true><<<eblocks, 256, 0, stream>>>(
            emb, hbuf, y14, sdp, atom_type, wlin_in,
            mw1, mb1, w2f, aggs, aggx, aggy, aggz, E);
    } else {
        edge_msg_mfma_l0<false><<<eblocks, 256, 0, stream>>>(
            emb, nullptr, y14, sdp, atom_type, wlin_in,
            mw1, mb1, w2f, aggs, aggx, aggy, aggz, E);
    }
    // node L0 + (fused) pre for L1
    node_update_mfma<<<nblocks + (nh ? pblocks : 0), 256, 0, stream>>>(
        nf, aggs, aggx, aggy, aggz, wgtf, atom_type, wlin_in, wl12,
        (float*)d_out, 1, 0, N,
        emb, mw1 + 1 * 8 * 64, mb1 + 1 * 64, hbuf, E, nblocks);

    // ---- Layers 1..2 ----
    for (int L = 1; L < 3; L++) {
        if (nh) {
            edge_msg_mfma<true><<<eblocks, 256, 0, stream>>>(
                emb, hbuf, y14, sdp, nf,
                mw1 + L * 8 * 64, mb1 + L * 64, w2f + (size_t)L * 20480,
                aggs, aggx, aggy, aggz, E);
        } else {
            edge_msg_mfma<false><<<eblocks, 256, 0, stream>>>(
                emb, nullptr, y14, sdp, nf,
                mw1 + L * 8 * 64, mb1 + L * 64, w2f + (size_t)L * 20480,
                aggs, aggx, aggy, aggz, E);
        }
        // node L + (fused) pre for L+1 (only when a next layer exists)
        int fuse = (nh && L < 2) ? pblocks : 0;
        // R30 FIX: nb_node must equal the real main-block count (nblocks)
        // for the swizzle bijection; when fuse==0 the tail branch is
        // unreachable anyway since gridDim == nblocks.
        node_update_mfma<<<nblocks + fuse, 256, 0, stream>>>(
            nf, aggs, aggx, aggy, aggz,
            wgtf + (size_t)L * 12288, atom_type, wlin_in, wl12,
            (float*)d_out, 0, (L == 2) ? 1 : 0, N,
            emb, mw1 + (L+1 < 3 ? L+1 : 0) * 8 * 64,
            mb1 + (L+1 < 3 ? L+1 : 0) * 64, hbuf, E,
            nblocks);
    }
}